// Round 14
// baseline (6747.195 us; speedup 1.0000x reference)
//
#include <hip/hip_runtime.h>
#include <hip/hip_bf16.h>

#define VOCAB  32000
#define DIM    1024
#define NLAYER 4
#define NB     8
#define SEQ    512

#define NGROUP       4
#define GBLKS        64
#define SCAN_BLOCKS  (NGROUP * GBLKS)      // 256
#define SCAN_THREADS 512                   // 8 waves, role-split

typedef __attribute__((ext_vector_type(8))) short          bf16x8;
typedef __attribute__((ext_vector_type(4))) float          f32x4;
typedef __attribute__((ext_vector_type(2))) float          f32x2;
typedef __attribute__((ext_vector_type(8))) unsigned short u16x8;
typedef __attribute__((ext_vector_type(4))) unsigned short u16x4;
typedef __attribute__((ext_vector_type(8))) _Float16       h8f;
typedef __attribute__((ext_vector_type(4))) _Float16       h4f;

__device__ __forceinline__ u16x8 cvt8_bf16(const float* p) {
    float4 f0 = *(const float4*)p;
    float4 f1 = *(const float4*)(p + 4);
    union { __hip_bfloat16 h[8]; u16x8 v; } u;
    u.h[0] = __float2bfloat16(f0.x); u.h[1] = __float2bfloat16(f0.y);
    u.h[2] = __float2bfloat16(f0.z); u.h[3] = __float2bfloat16(f0.w);
    u.h[4] = __float2bfloat16(f1.x); u.h[5] = __float2bfloat16(f1.y);
    u.h[6] = __float2bfloat16(f1.z); u.h[7] = __float2bfloat16(f1.w);
    return u.v;
}

__device__ __forceinline__ h8f pack8(f32x4 a, f32x4 b) {
    h8f o;
    o[0] = (_Float16)a[0]; o[1] = (_Float16)a[1];
    o[2] = (_Float16)a[2]; o[3] = (_Float16)a[3];
    o[4] = (_Float16)b[0]; o[5] = (_Float16)b[1];
    o[6] = (_Float16)b[2]; o[7] = (_Float16)b[3];
    return o;
}

// ---- coherence-point (L3) accesses: bypass per-XCD L2, so no cache fences ----
__device__ __forceinline__ void ld4v(f32x4& d, const float* p) {
    asm volatile("global_load_dwordx4 %0, %1, off sc0 sc1"
                 : "=&v"(d) : "v"(p));
}
__device__ __forceinline__ void st8v(void* p, f32x2 v) {
    asm volatile("global_store_dwordx2 %0, %1, off sc0 sc1"
                 :: "v"(p), "v"(v) : "memory");
}
__device__ __forceinline__ void st2v(void* p, unsigned v) {
    asm volatile("global_store_short %0, %1, off sc0 sc1"
                 :: "v"(p), "v"(v) : "memory");
}
__device__ __forceinline__ void vmwait0() {
    asm volatile("s_waitcnt vmcnt(0)" ::: "memory");
}

// ---------------------------------------------------------------------------
__global__ void bar_init_kernel(unsigned* __restrict__ bar) {
    bar[threadIdx.x]        = 0u;
    bar[threadIdx.x + 1024] = 0u;
    bar[threadIdx.x + 2048] = 0u;
    bar[threadIdx.x + 3072] = 0u;   // 4096 words = 16 KiB
}

// ---------------------------------------------------------------------------
// Fence-free slot barrier (round-12 form: single-wave poll + exit sync —
// round 13 showed all-wave polling is slightly worse).
// ---------------------------------------------------------------------------
__device__ __forceinline__ void slot_bar(unsigned* __restrict__ slots, int bkg,
                                         unsigned seq, bool& dead) {
    __syncthreads();
    const int tid = threadIdx.x;
    if (tid == 0)
        __hip_atomic_store(&slots[bkg * 8], seq, __ATOMIC_RELAXED,
                           __HIP_MEMORY_SCOPE_AGENT);
    if (tid < 64 && !dead) {
        unsigned guard = 0;
        for (;;) {
            unsigned v = __hip_atomic_load(&slots[tid * 8], __ATOMIC_RELAXED,
                                           __HIP_MEMORY_SCOPE_AGENT);
            if (__all((int)(v >= seq))) break;
            __builtin_amdgcn_s_sleep(1);
            if (++guard > (1u << 16)) { dead = true; break; }
        }
    }
    __syncthreads();
}

// ---------------------------------------------------------------------------
// MFMA layer-pipelined persistent-weight GRU scan, LDS-staging-free:
// MFMA B-operands are loaded straight from the fp16 h-ring / rh-buffer in
// ws (sc1 = L3 coherence point) into registers. Wave roles:
//  w0-3: z+r K-quarters (w0/w1 = x-half quarters, w2/w3 = h-half quarters)
//  w4-5: candA x-half K-halves (phase A) / candB rh K-halves (phase B)
//  w6:   z-combine + state update (fp32 hold in regs; publishes h fp16 + ysf bf16)
//  w7:   r-combine -> rh = r * h(t-1) (via hb LDS handoff from w6) -> rbuf fp16
// ---------------------------------------------------------------------------
__global__ void __launch_bounds__(SCAN_THREADS)
__attribute__((amdgpu_waves_per_eu(2, 2)))
gru_scan(
    const int*   __restrict__ ids,     // [NB][SEQ]
    const float* __restrict__ embW,    // [VOCAB][DIM] fp32
    const float* __restrict__ hstart,  // [NLAYER][DIM]
    const float* __restrict__ gW,      // [NLAYER][2*DIM][2*DIM]
    const float* __restrict__ gB,      // [NLAYER][2*DIM]
    const float* __restrict__ cW,      // [NLAYER][DIM][2*DIM]
    const float* __restrict__ cB,      // [NLAYER][DIM]
    _Float16* __restrict__ hbuf16,     // [4][NLAYER][NB][DIM] fp16 ring
    _Float16* __restrict__ rbuf16,     // [NGROUP][NB][DIM] fp16 (rh)
    __hip_bfloat16* __restrict__ ysfb, // [NB][SEQ][DIM] bf16
    unsigned* __restrict__ bar)
{
    __shared__ float pz[4][4][64];
    __shared__ float pr[4][4][64];
    __shared__ float pc[2][4][64];
    __shared__ float pcb[2][4][64];
    __shared__ float hb[4][64];        // h(t-1) handoff w6 -> w7

    const int tid   = threadIdx.x;
    const int lane  = tid & 63;
    const int wv    = tid >> 6;               // 0..7
    const int l15   = lane & 15;
    const int lgq   = lane >> 4;              // 0..3
    const int bcol  = l15 & 7;                // batch (cols 8..15 dup 0..7)
    const int g     = blockIdx.x >> 6;        // layer group
    const int bkg   = blockIdx.x & (GBLKS-1);
    const int jbase = bkg * 16;
    const int jrow  = jbase + l15;            // this lane's A row

    const bool xwave = (wv == 0 || wv == 1 || wv == 4 || wv == 5);
    const int  xoff  = (wv == 1 || wv == 5) ? 512 : 0;   // x k-offset
    const int  hoff  = (wv == 3) ? 512 : 0;              // h k-offset (w2/w3)

    // ---- persistent fp16 A-fragment weights (pinned; unified VGPR/AGPR) ----
    h8f Wa[16], Wb[16];
    if (wv < 6) {
        const float* wzp = gW + ((size_t)g * 2048 + jrow) * 2048;
        const float* wrp = gW + ((size_t)g * 2048 + 1024 + jrow) * 2048;
        const float* wcp = cW + ((size_t)g * 1024 + jrow) * 2048;
        const float* baseA; const float* baseB; int koA, koB;
        switch (wv) {
          case 0:  baseA = wzp; koA = 0;    baseB = wrp; koB = 0;    break;
          case 1:  baseA = wzp; koA = 512;  baseB = wrp; koB = 512;  break;
          case 2:  baseA = wzp; koA = 1024; baseB = wrp; koB = 1024; break;
          case 3:  baseA = wzp; koA = 1536; baseB = wrp; koB = 1536; break;
          case 4:  baseA = wcp; koA = 0;    baseB = wcp; koB = 1024; break;
          default: baseA = wcp; koA = 512;  baseB = wcp; koB = 1536; break;
        }
        #pragma unroll
        for (int kc = 0; kc < 16; ++kc) {
            const int ka = koA + kc * 32 + lgq * 8;
            const int kb = koB + kc * 32 + lgq * 8;
            Wa[kc] = pack8(*(const f32x4*)(baseA + ka), *(const f32x4*)(baseA + ka + 4));
            Wb[kc] = pack8(*(const f32x4*)(baseB + kb), *(const f32x4*)(baseB + kb + 4));
        }
        #pragma unroll
        for (int kc = 0; kc < 16; ++kc) {
            asm volatile("" : "+v"(Wa[kc]));
            asm volatile("" : "+v"(Wb[kc]));
        }
    }

    float bz4[4], br4[4], cb4[4], hold[4], zreg[4];
    if (wv == 6) {
        #pragma unroll
        for (int r = 0; r < 4; ++r) {
            const int j = jbase + lgq * 4 + r;
            bz4[r]  = gB[g * 2048 + j];
            cb4[r]  = cB[g * 1024 + j];
            hold[r] = hstart[g * 1024 + j];
            hb[r][lane] = hold[r];
        }
    }
    if (wv == 7) {
        #pragma unroll
        for (int r = 0; r < 4; ++r)
            br4[r] = gB[g * 2048 + 1024 + jbase + lgq * 4 + r];
    }

    bool dead = false;
    unsigned* slots1g = bar + g * 512;
    unsigned* slots2g = bar + 2048 + g * 512;
    unsigned* s2prev  = (g > 0)          ? bar + 2048 + (g - 1) * 512 : nullptr;
    unsigned* s1next  = (g < NGROUP - 1) ? bar + (g + 1) * 512        : nullptr;
    _Float16* rbufg16 = rbuf16 + (size_t)g * NB * DIM;

    // init own layer h(-1) into ring slot 3 (fp16, sc1)
    if (tid < 128) {
        int e = bkg * 128 + tid;   // 0..8191 over [NB][DIM]
        union { _Float16 h; unsigned short u; } cv;
        cv.h = (_Float16)hstart[g * DIM + (e & (DIM - 1))];
        st2v(&hbuf16[((size_t)3 * NLAYER + g) * NB * DIM + e], (unsigned)cv.u);
    }
    slot_bar(slots2g, bkg, 1u, dead);

    for (int t = 0; t < SEQ; ++t) {
        const int so = (t + 3) & 3;   // h_old slot
        const int sw = t & 3;         // h_new slot
        const _Float16* hsrc16 = hbuf16 + ((size_t)so * NLAYER + g) * NB * DIM;
        _Float16*       hdst16 = hbuf16 + ((size_t)sw * NLAYER + g) * NB * DIM;
        const _Float16* xprev16 = hbuf16 + ((size_t)sw * NLAYER + (g > 0 ? g - 1 : 0)) * NB * DIM;

        // ---- per-wave peer gates ----
        if (g > 0 && xwave && !dead) {           // x ready: prev group bar2(t)
            const unsigned need = (unsigned)(t + 2);
            unsigned guard = 0;
            for (;;) {
                unsigned v = __hip_atomic_load(&s2prev[lane * 8], __ATOMIC_RELAXED,
                                               __HIP_MEMORY_SCOPE_AGENT);
                if (__all((int)(v >= need))) break;
                __builtin_amdgcn_s_sleep(1);
                if (++guard > (1u << 16)) { dead = true; break; }
            }
        }
        if (wv == 6 && g < NGROUP - 1 && t >= 4 && !dead) {  // ring slot free
            const unsigned need = (unsigned)(t - 3);
            unsigned guard = 0;
            for (;;) {
                unsigned v = __hip_atomic_load(&s1next[lane * 8], __ATOMIC_RELAXED,
                                               __HIP_MEMORY_SCOPE_AGENT);
                if (__all((int)(v >= need))) break;
                __builtin_amdgcn_s_sleep(1);
                if (++guard > (1u << 16)) { dead = true; break; }
            }
        }

        // ---- Phase A: MFMA dots, B-operand straight from L3 ----
        if (wv < 6) {
            f32x4 accA = {0.f, 0.f, 0.f, 0.f};
            f32x4 accB = {0.f, 0.f, 0.f, 0.f};
            if (g == 0 && xwave) {
                // embedding rows are fp32: 2 chunks of 8 kc, convert in regs
                const int erow = ids[bcol * SEQ + t];
                const float* ep = embW + (size_t)erow * DIM + xoff;
                #pragma unroll
                for (int c = 0; c < 2; ++c) {
                    f32x4 c0[8], c1[8];
                    #pragma unroll
                    for (int k8 = 0; k8 < 8; ++k8) {
                        const float* p = ep + (c * 8 + k8) * 32 + lgq * 8;
                        ld4v(c0[k8], p);
                        ld4v(c1[k8], p + 4);
                    }
                    vmwait0();
                    #pragma unroll
                    for (int k8 = 0; k8 < 8; ++k8) {
                        asm volatile("" : "+v"(c0[k8]));
                        asm volatile("" : "+v"(c1[k8]));
                    }
                    #pragma unroll
                    for (int k8 = 0; k8 < 8; ++k8) {
                        const int kc = c * 8 + k8;
                        const h8f bf = pack8(c0[k8], c1[k8]);
                        accA = __builtin_amdgcn_mfma_f32_16x16x32_f16(Wa[kc], bf, accA, 0, 0, 0);
                        if (wv < 4)
                            accB = __builtin_amdgcn_mfma_f32_16x16x32_f16(Wb[kc], bf, accB, 0, 0, 0);
                    }
                }
            } else {
                const _Float16* bsrc = xwave ? (xprev16 + (size_t)bcol * DIM + xoff)
                                             : (hsrc16 + (size_t)bcol * DIM + hoff);
                f32x4 braw[16];
                #pragma unroll
                for (int kc = 0; kc < 16; ++kc)
                    ld4v(braw[kc], (const float*)(bsrc + kc * 32 + lgq * 8));
                vmwait0();
                #pragma unroll
                for (int kc = 0; kc < 16; ++kc)
                    asm volatile("" : "+v"(braw[kc]));
                #pragma unroll
                for (int kc = 0; kc < 16; ++kc) {
                    const h8f bf = __builtin_bit_cast(h8f, braw[kc]);
                    accA = __builtin_amdgcn_mfma_f32_16x16x32_f16(Wa[kc], bf, accA, 0, 0, 0);
                    if (wv < 4)
                        accB = __builtin_amdgcn_mfma_f32_16x16x32_f16(Wb[kc], bf, accB, 0, 0, 0);
                }
            }
            if (wv < 4) {
                #pragma unroll
                for (int r = 0; r < 4; ++r) {
                    pz[wv][r][lane] = accA[r];
                    pr[wv][r][lane] = accB[r];
                }
            } else {
                #pragma unroll
                for (int r = 0; r < 4; ++r) pc[wv - 4][r][lane] = accA[r];
            }
        }
        __syncthreads();   // S1: partials ready

        // ---- combine: z (w6, regs) ; r -> rh (w7 -> rbuf fp16 sc1) ----
        if (wv == 6) {
            #pragma unroll
            for (int r = 0; r < 4; ++r) {
                const float s = pz[0][r][lane] + pz[1][r][lane]
                              + pz[2][r][lane] + pz[3][r][lane] + bz4[r];
                zreg[r] = 1.f / (1.f + expf(-s));
            }
        }
        if (wv == 7) {
            h4f rh4;
            #pragma unroll
            for (int r = 0; r < 4; ++r) {
                const float s = pr[0][r][lane] + pr[1][r][lane]
                              + pr[2][r][lane] + pr[3][r][lane] + br4[r];
                const float rg = 1.f / (1.f + expf(-s));
                rh4[r] = (_Float16)(rg * hb[r][lane]);
            }
            if (l15 < 8)
                st8v(rbufg16 + (size_t)bcol * DIM + jbase + lgq * 4,
                     __builtin_bit_cast(f32x2, rh4));
        }
        // bar1: rh published / x consumed
        slot_bar(slots1g, bkg, (unsigned)(t + 1), dead);

        // ---- Phase B: candB MFMA over rh (loaded straight from L3) ----
        if (wv == 4 || wv == 5) {
            const _Float16* rsrc = rbufg16 + (size_t)bcol * DIM + ((wv == 5) ? 512 : 0);
            f32x4 rraw[16];
            #pragma unroll
            for (int kc = 0; kc < 16; ++kc)
                ld4v(rraw[kc], (const float*)(rsrc + kc * 32 + lgq * 8));
            vmwait0();
            #pragma unroll
            for (int kc = 0; kc < 16; ++kc)
                asm volatile("" : "+v"(rraw[kc]));
            f32x4 acc = {0.f, 0.f, 0.f, 0.f};
            #pragma unroll
            for (int kc = 0; kc < 16; ++kc)
                acc = __builtin_amdgcn_mfma_f32_16x16x32_f16(
                    Wb[kc], __builtin_bit_cast(h8f, rraw[kc]), acc, 0, 0, 0);
            #pragma unroll
            for (int r = 0; r < 4; ++r) pcb[wv - 4][r][lane] = acc[r];
        }
        __syncthreads();   // S2: candB partials ready

        // ---- update (w6): cand = tanh(cA+cB+b), h = z*h + (1-z)*cand ----
        if (wv == 6) {
            h4f hp; u16x4 yp;
            #pragma unroll
            for (int r = 0; r < 4; ++r) {
                const float cand = tanhf(pc[0][r][lane] + pc[1][r][lane]
                                         + pcb[0][r][lane] + pcb[1][r][lane] + cb4[r]);
                const float hn = zreg[r] * hold[r] + (1.f - zreg[r]) * cand;
                hold[r] = hn;
                hb[r][lane] = hn;
                hp[r] = (_Float16)hn;
                union { __hip_bfloat16 b; unsigned short u; } cv;
                cv.b = __float2bfloat16(hn);
                yp[r] = cv.u;
            }
            if (l15 < 8) {
                st8v(hdst16 + (size_t)bcol * DIM + jbase + lgq * 4,
                     __builtin_bit_cast(f32x2, hp));
                if (g == NGROUP - 1)
                    *(f32x2*)(ysfb + ((size_t)bcol * SEQ + t) * DIM + jbase + lgq * 4) =
                        __builtin_bit_cast(f32x2, yp);
            }
        }
        // bar2: h(t) published
        slot_bar(slots2g, bkg, (unsigned)(t + 2), dead);
    }

    if (dead && tid == 0) {
        union { __hip_bfloat16 b; unsigned short u; } cv;
        cv.b = __float2bfloat16(1.0e8f);
        ((unsigned short*)ysfb)[blockIdx.x] = cv.u;   // unmistakable sentinel
    }
}

// ---------------------------------------------------------------------------
// Logits GEMM: C[m][n] = sum_k ys[m][k] * outW[n][k]
// A is now bf16 (direct copy into LDS); B fp32 converted during staging.
// ---------------------------------------------------------------------------
#define BM 128
#define BN 128
#define BK 64

__global__ void __launch_bounds__(256) out_gemm(
    const __hip_bfloat16* __restrict__ A,   // [4096][1024] bf16
    const float* __restrict__ B,            // [32000][1024] fp32
    float* __restrict__ C)                  // [4096][32000]
{
    __shared__ __hip_bfloat16 At[BM][BK + 8];
    __shared__ __hip_bfloat16 Bt[BN][BK + 8];

    const int tid  = threadIdx.x;
    const int lane = tid & 63;
    const int wv   = tid >> 6;
    const int wm   = wv >> 1, wn = wv & 1;
    const int m0   = blockIdx.y * BM;
    const int n0   = blockIdx.x * BN;

    f32x4 acc[4][4];
    #pragma unroll
    for (int i = 0; i < 4; ++i)
        #pragma unroll
        for (int jj = 0; jj < 4; ++jj)
            acc[i][jj] = (f32x4){0.f, 0.f, 0.f, 0.f};

    const int srow = tid >> 3;           // 0..31
    const int scol = (tid & 7) * 8;      // 0..56
    const int l15  = lane & 15;
    const int l4   = lane >> 4;

    for (int kt = 0; kt < DIM / BK; ++kt) {
        const int k0 = kt * BK;
        #pragma unroll
        for (int rnd = 0; rnd < 4; ++rnd) {
            const int row = rnd * 32 + srow;
            *(u16x8*)&At[row][scol] =
                *(const u16x8*)&A[(size_t)(m0 + row) * DIM + k0 + scol];
            *(u16x8*)&Bt[row][scol] =
                cvt8_bf16(&B[(size_t)(n0 + row) * DIM + k0 + scol]);
        }
        __syncthreads();
        #pragma unroll
        for (int ks = 0; ks < 2; ++ks) {
            bf16x8 av[4], bv[4];
            #pragma unroll
            for (int i = 0; i < 4; ++i) {
                av[i] = *(const bf16x8*)&At[wm * 64 + i * 16 + l15][ks * 32 + l4 * 8];
                bv[i] = *(const bf16x8*)&Bt[wn * 64 + i * 16 + l15][ks * 32 + l4 * 8];
            }
            #pragma unroll
            for (int i = 0; i < 4; ++i)
                #pragma unroll
                for (int jj = 0; jj < 4; ++jj)
                    acc[i][jj] = __builtin_amdgcn_mfma_f32_16x16x32_bf16(
                        av[i], bv[jj], acc[i][jj], 0, 0, 0);
        }
        __syncthreads();
    }

    const int rq = l4 * 4;
    #pragma unroll
    for (int i = 0; i < 4; ++i) {
        const int rbase = m0 + wm * 64 + i * 16 + rq;
        #pragma unroll
        for (int jj = 0; jj < 4; ++jj) {
            const int col = n0 + wn * 64 + jj * 16 + l15;
            #pragma unroll
            for (int r2 = 0; r2 < 4; ++r2)
                C[(size_t)(rbase + r2) * VOCAB + col] = acc[i][jj][r2];
        }
    }
}

// ---------------------------------------------------------------------------
extern "C" void kernel_launch(void* const* d_in, const int* in_sizes, int n_in,
                              void* d_out, int out_size, void* d_ws, size_t ws_size,
                              hipStream_t stream)
{
    (void)in_sizes; (void)n_in; (void)out_size; (void)ws_size;
    const int*   ids  = (const int*)  d_in[0];
    const float* embW = (const float*)d_in[1];
    const float* hst  = (const float*)d_in[2];
    const float* gW   = (const float*)d_in[3];
    const float* gB   = (const float*)d_in[4];
    const float* cW   = (const float*)d_in[5];
    const float* cB   = (const float*)d_in[6];
    const float* outW = (const float*)d_in[7];
    float* logits = (float*)d_out;

    // workspace carve-up (~8.7 MiB)
    char* ws = (char*)d_ws;
    unsigned*       bar     = (unsigned*)ws;                       // 16 KiB
    _Float16*       rbuf16  = (_Float16*)(ws + 16384);             // 64 KiB
    _Float16*       hbuf16  = (_Float16*)(ws + 16384 + 65536);     // 256 KiB
    __hip_bfloat16* ysfb    = (__hip_bfloat16*)(ws + 16384 + 65536 + 262144);  // 8 MiB

    // 1) zero slot arrays
    bar_init_kernel<<<dim3(1), dim3(1024), 0, stream>>>(bar);

    // 2) MFMA layer-pipelined persistent-weight GRU scan (no LDS staging)
    gru_scan<<<dim3(SCAN_BLOCKS), dim3(SCAN_THREADS), 0, stream>>>(
        ids, embW, hst, gW, gB, cW, cB, hbuf16, rbuf16, ysfb, bar);

    // 3) logits GEMM (bf16 A, fp32 B)
    out_gemm<<<dim3(VOCAB / BN, (NB * SEQ) / BM), dim3(256), 0, stream>>>(ysfb, outW, logits);
}

// Round 15
// 6366.788 us; speedup vs baseline: 1.0597x; 1.0597x over previous
//
#include <hip/hip_runtime.h>
#include <hip/hip_bf16.h>

#define VOCAB  32000
#define DIM    1024
#define NLAYER 4
#define NB     8
#define SEQ    512

#define NGROUP       4
#define GBLKS        64
#define SCAN_BLOCKS  (NGROUP * GBLKS)      // 256
#define SCAN_THREADS 512                   // 8 waves, role-split
#define ROWH         2056                  // act row stride in halves (1024 x + pad-friendly)

typedef __attribute__((ext_vector_type(8))) short          bf16x8;
typedef __attribute__((ext_vector_type(4))) float          f32x4;
typedef __attribute__((ext_vector_type(2))) float          f32x2;
typedef __attribute__((ext_vector_type(8))) unsigned short u16x8;
typedef __attribute__((ext_vector_type(4))) unsigned short u16x4;
typedef __attribute__((ext_vector_type(8))) _Float16       h8f;
typedef __attribute__((ext_vector_type(4))) _Float16       h4f;

__device__ __forceinline__ u16x8 cvt8_bf16(const float* p) {
    float4 f0 = *(const float4*)p;
    float4 f1 = *(const float4*)(p + 4);
    union { __hip_bfloat16 h[8]; u16x8 v; } u;
    u.h[0] = __float2bfloat16(f0.x); u.h[1] = __float2bfloat16(f0.y);
    u.h[2] = __float2bfloat16(f0.z); u.h[3] = __float2bfloat16(f0.w);
    u.h[4] = __float2bfloat16(f1.x); u.h[5] = __float2bfloat16(f1.y);
    u.h[6] = __float2bfloat16(f1.z); u.h[7] = __float2bfloat16(f1.w);
    return u.v;
}

__device__ __forceinline__ h8f pack8(f32x4 a, f32x4 b) {
    h8f o;
    o[0] = (_Float16)a[0]; o[1] = (_Float16)a[1];
    o[2] = (_Float16)a[2]; o[3] = (_Float16)a[3];
    o[4] = (_Float16)b[0]; o[5] = (_Float16)b[1];
    o[6] = (_Float16)b[2]; o[7] = (_Float16)b[3];
    return o;
}

// ---- coherence-point (L3) accesses: bypass per-XCD L2 (no cache fences) ----
__device__ __forceinline__ void ld4v(f32x4& d, const float* p) {
    asm volatile("global_load_dwordx4 %0, %1, off sc0 sc1"
                 : "=&v"(d) : "v"(p));
}
__device__ __forceinline__ void st8v(void* p, f32x2 v) {
    asm volatile("global_store_dwordx2 %0, %1, off sc0 sc1"
                 :: "v"(p), "v"(v) : "memory");
}
__device__ __forceinline__ void st2v(void* p, unsigned v) {
    asm volatile("global_store_short %0, %1, off sc0 sc1"
                 :: "v"(p), "v"(v) : "memory");
}
__device__ __forceinline__ void vmwait0() {
    asm volatile("s_waitcnt vmcnt(0)" ::: "memory");
}

// ---------------------------------------------------------------------------
__global__ void bar_init_kernel(unsigned* __restrict__ bar) {
    bar[threadIdx.x]        = 0u;
    bar[threadIdx.x + 1024] = 0u;
    bar[threadIdx.x + 2048] = 0u;
    bar[threadIdx.x + 3072] = 0u;   // 4096 words = 16 KiB
}

// ---------------------------------------------------------------------------
// Fence-free slot barrier (round-12 form — proven best).
// ---------------------------------------------------------------------------
__device__ __forceinline__ void slot_bar(unsigned* __restrict__ slots, int bkg,
                                         unsigned seq, bool& dead) {
    __syncthreads();
    const int tid = threadIdx.x;
    if (tid == 0)
        __hip_atomic_store(&slots[bkg * 8], seq, __ATOMIC_RELAXED,
                           __HIP_MEMORY_SCOPE_AGENT);
    if (tid < 64 && !dead) {
        unsigned guard = 0;
        for (;;) {
            unsigned v = __hip_atomic_load(&slots[tid * 8], __ATOMIC_RELAXED,
                                           __HIP_MEMORY_SCOPE_AGENT);
            if (__all((int)(v >= seq))) break;
            __builtin_amdgcn_s_sleep(1);
            if (++guard > (1u << 16)) { dead = true; break; }
        }
    }
    __syncthreads();
}

// ---------------------------------------------------------------------------
// MFMA layer-pipelined persistent-weight GRU scan, reuse-driven staging:
//  x (2x reuse: w0/w4, w1/w5)     -> staged once into LDS (fp16)
//  h slices (w2/w3, disjoint)     -> direct sc1 loads from fp16 ring
//  rh slices (w4/w5, disjoint)    -> direct sc1 loads from fp16 rbuf
// Wave roles: w0/w1 z+r x-halves (LDS); w2/w3 z+r h-halves (direct);
// w4/w5 candA x-halves (LDS) then candB rh-halves (direct);
// w6 z-combine + update (+h publish, ysf bf16); w7 r-combine -> rh publish.
// ---------------------------------------------------------------------------
__global__ void __launch_bounds__(SCAN_THREADS)
__attribute__((amdgpu_waves_per_eu(2, 2)))
gru_scan(
    const int*   __restrict__ ids,     // [NB][SEQ]
    const float* __restrict__ embW,    // [VOCAB][DIM] fp32
    const float* __restrict__ hstart,  // [NLAYER][DIM]
    const float* __restrict__ gW,      // [NLAYER][2*DIM][2*DIM]
    const float* __restrict__ gB,      // [NLAYER][2*DIM]
    const float* __restrict__ cW,      // [NLAYER][DIM][2*DIM]
    const float* __restrict__ cB,      // [NLAYER][DIM]
    _Float16* __restrict__ hbuf16,     // [4][NLAYER][NB][DIM] fp16 ring
    _Float16* __restrict__ rbuf16,     // [NGROUP][NB][DIM] fp16 (rh)
    __hip_bfloat16* __restrict__ ysfb, // [NB][SEQ][DIM] bf16
    unsigned* __restrict__ bar)
{
    __shared__ _Float16 act[NB * ROWH];    // 32,896 B: x (fp16), per-batch rows
    __shared__ float pz[4][4][64];
    __shared__ float pr[4][4][64];
    __shared__ float pc[2][4][64];
    __shared__ float pcb[2][4][64];
    __shared__ float hb[4][64];            // h(t-1) handoff w6 -> w7

    const int tid   = threadIdx.x;
    const int lane  = tid & 63;
    const int wv    = tid >> 6;               // 0..7
    const int l15   = lane & 15;
    const int lgq   = lane >> 4;              // 0..3
    const int bcol  = l15 & 7;                // batch (cols 8..15 dup 0..7)
    const int g     = blockIdx.x >> 6;        // layer group
    const int bkg   = blockIdx.x & (GBLKS-1);
    const int jbase = bkg * 16;
    const int jrow  = jbase + l15;            // this lane's A row

    const bool stager = (wv == 0 || wv == 1 || wv == 4 || wv == 5);
    const int  xoff   = (wv == 1 || wv == 5) ? 512 : 0;   // x k-offset
    const int  hoff   = (wv == 3) ? 512 : 0;              // h k-offset (w2/w3)

    // ---- persistent fp16 A-fragment weights (pinned; unified VGPR/AGPR) ----
    h8f Wa[16], Wb[16];
    if (wv < 6) {
        const float* wzp = gW + ((size_t)g * 2048 + jrow) * 2048;
        const float* wrp = gW + ((size_t)g * 2048 + 1024 + jrow) * 2048;
        const float* wcp = cW + ((size_t)g * 1024 + jrow) * 2048;
        const float* baseA; const float* baseB; int koA, koB;
        switch (wv) {
          case 0:  baseA = wzp; koA = 0;    baseB = wrp; koB = 0;    break;
          case 1:  baseA = wzp; koA = 512;  baseB = wrp; koB = 512;  break;
          case 2:  baseA = wzp; koA = 1024; baseB = wrp; koB = 1024; break;
          case 3:  baseA = wzp; koA = 1536; baseB = wrp; koB = 1536; break;
          case 4:  baseA = wcp; koA = 0;    baseB = wcp; koB = 1024; break;
          default: baseA = wcp; koA = 512;  baseB = wcp; koB = 1536; break;
        }
        #pragma unroll
        for (int kc = 0; kc < 16; ++kc) {
            const int ka = koA + kc * 32 + lgq * 8;
            const int kb = koB + kc * 32 + lgq * 8;
            Wa[kc] = pack8(*(const f32x4*)(baseA + ka), *(const f32x4*)(baseA + ka + 4));
            Wb[kc] = pack8(*(const f32x4*)(baseB + kb), *(const f32x4*)(baseB + kb + 4));
        }
        #pragma unroll
        for (int kc = 0; kc < 16; ++kc) {
            asm volatile("" : "+v"(Wa[kc]));
            asm volatile("" : "+v"(Wb[kc]));
        }
    }

    float bz4[4], br4[4], cb4[4], hold[4], zreg[4];
    if (wv == 6) {
        #pragma unroll
        for (int r = 0; r < 4; ++r) {
            const int j = jbase + lgq * 4 + r;
            bz4[r]  = gB[g * 2048 + j];
            cb4[r]  = cB[g * 1024 + j];
            hold[r] = hstart[g * 1024 + j];
            hb[r][lane] = hold[r];
        }
    }
    if (wv == 7) {
        #pragma unroll
        for (int r = 0; r < 4; ++r)
            br4[r] = gB[g * 2048 + 1024 + jbase + lgq * 4 + r];
    }

    bool dead = false;
    unsigned* slots1g = bar + g * 512;
    unsigned* slots2g = bar + 2048 + g * 512;
    unsigned* s2prev  = (g > 0)          ? bar + 2048 + (g - 1) * 512 : nullptr;
    unsigned* s1next  = (g < NGROUP - 1) ? bar + (g + 1) * 512        : nullptr;
    _Float16* rbufg16 = rbuf16 + (size_t)g * NB * DIM;

    // init own layer h(-1) into ring slot 3 (fp16, sc1)
    if (tid < 128) {
        int e = bkg * 128 + tid;   // 0..8191 over [NB][DIM]
        union { _Float16 h; unsigned short u; } cv;
        cv.h = (_Float16)hstart[g * DIM + (e & (DIM - 1))];
        st2v(&hbuf16[((size_t)3 * NLAYER + g) * NB * DIM + e], (unsigned)cv.u);
    }
    slot_bar(slots2g, bkg, 1u, dead);

    for (int t = 0; t < SEQ; ++t) {
        const int so = (t + 3) & 3;   // h_old slot
        const int sw = t & 3;         // h_new slot
        const _Float16* hsrc16  = hbuf16 + ((size_t)so * NLAYER + g) * NB * DIM;
        _Float16*       hdst16  = hbuf16 + ((size_t)sw * NLAYER + g) * NB * DIM;
        const _Float16* xprev16 = hbuf16 + ((size_t)sw * NLAYER + (g > 0 ? g - 1 : 0)) * NB * DIM;

        // ---- per-wave gates ----
        if (g > 0 && stager && !dead) {           // x ready: prev group bar2(t)
            const unsigned need = (unsigned)(t + 2);
            unsigned guard = 0;
            for (;;) {
                unsigned v = __hip_atomic_load(&s2prev[lane * 8], __ATOMIC_RELAXED,
                                               __HIP_MEMORY_SCOPE_AGENT);
                if (__all((int)(v >= need))) break;
                __builtin_amdgcn_s_sleep(1);
                if (++guard > (1u << 16)) { dead = true; break; }
            }
        }
        if (wv == 6 && g < NGROUP - 1 && t >= 4 && !dead) {  // ring slot free
            const unsigned need = (unsigned)(t - 3);
            unsigned guard = 0;
            for (;;) {
                unsigned v = __hip_atomic_load(&s1next[lane * 8], __ATOMIC_RELAXED,
                                               __HIP_MEMORY_SCOPE_AGENT);
                if (__all((int)(v >= need))) break;
                __builtin_amdgcn_s_sleep(1);
                if (++guard > (1u << 16)) { dead = true; break; }
            }
        }

        // ---- stage x -> act (fp16), 256 stager threads, 4 h8f units each ----
        if (stager) {
            const int sidx = ((wv < 2) ? wv : (wv - 2)) * 64 + lane;   // 0..255
            if (g == 0) {
                #pragma unroll
                for (int q = 0; q < 4; ++q) {
                    const int u  = q * 256 + sidx;
                    const int b  = u >> 7, d8 = (u & 127) * 8;
                    const int row = ids[b * SEQ + t];
                    const float* p = embW + (size_t)row * DIM + d8;
                    *(h8f*)&act[b * ROWH + d8] =
                        pack8(*(const f32x4*)p, *(const f32x4*)(p + 4));
                }
            } else {
                f32x4 tv[4];
                #pragma unroll
                for (int q = 0; q < 4; ++q) {
                    const int u = q * 256 + sidx;
                    ld4v(tv[q], (const float*)(xprev16 + (size_t)(u >> 7) * DIM + (u & 127) * 8));
                }
                vmwait0();
                asm volatile("" : "+v"(tv[0]), "+v"(tv[1]), "+v"(tv[2]), "+v"(tv[3]));
                #pragma unroll
                for (int q = 0; q < 4; ++q) {
                    const int u = q * 256 + sidx;
                    *(h8f*)&act[(u >> 7) * ROWH + (u & 127) * 8] =
                        __builtin_bit_cast(h8f, tv[q]);
                }
            }
        }
        __syncthreads();   // S0: x staged

        // ---- Phase A ----
        if (wv < 6) {
            f32x4 accA = {0.f, 0.f, 0.f, 0.f};
            f32x4 accB = {0.f, 0.f, 0.f, 0.f};
            if (wv == 2 || wv == 3) {
                // h-halves: direct sc1 loads (disjoint, no reuse)
                const _Float16* bsrc = hsrc16 + (size_t)bcol * DIM + hoff;
                f32x4 braw[16];
                #pragma unroll
                for (int kc = 0; kc < 16; ++kc)
                    ld4v(braw[kc], (const float*)(bsrc + kc * 32 + lgq * 8));
                vmwait0();
                #pragma unroll
                for (int kc = 0; kc < 16; ++kc)
                    asm volatile("" : "+v"(braw[kc]));
                #pragma unroll
                for (int kc = 0; kc < 16; ++kc) {
                    const h8f bf = __builtin_bit_cast(h8f, braw[kc]);
                    accA = __builtin_amdgcn_mfma_f32_16x16x32_f16(Wa[kc], bf, accA, 0, 0, 0);
                    accB = __builtin_amdgcn_mfma_f32_16x16x32_f16(Wb[kc], bf, accB, 0, 0, 0);
                }
            } else {
                // x-halves from LDS (w0/w1: z+r; w4/w5: candA)
                #pragma unroll
                for (int kc = 0; kc < 16; ++kc) {
                    const h8f bf = *(const h8f*)&act[bcol * ROWH + xoff + kc * 32 + lgq * 8];
                    accA = __builtin_amdgcn_mfma_f32_16x16x32_f16(Wa[kc], bf, accA, 0, 0, 0);
                    if (wv < 2)
                        accB = __builtin_amdgcn_mfma_f32_16x16x32_f16(Wb[kc], bf, accB, 0, 0, 0);
                }
            }
            if (wv < 4) {
                #pragma unroll
                for (int r = 0; r < 4; ++r) {
                    pz[wv][r][lane] = accA[r];
                    pr[wv][r][lane] = accB[r];
                }
            } else {
                #pragma unroll
                for (int r = 0; r < 4; ++r) pc[wv - 4][r][lane] = accA[r];
            }
        }
        __syncthreads();   // S1: partials ready

        // ---- combine: z (w6, regs) ; r -> rh publish (w7, fp16 sc1) ----
        if (wv == 6) {
            #pragma unroll
            for (int r = 0; r < 4; ++r) {
                const float s = pz[0][r][lane] + pz[1][r][lane]
                              + pz[2][r][lane] + pz[3][r][lane] + bz4[r];
                zreg[r] = 1.f / (1.f + expf(-s));
            }
        }
        if (wv == 7) {
            h4f rh4;
            #pragma unroll
            for (int r = 0; r < 4; ++r) {
                const float s = pr[0][r][lane] + pr[1][r][lane]
                              + pr[2][r][lane] + pr[3][r][lane] + br4[r];
                const float rg = 1.f / (1.f + expf(-s));
                rh4[r] = (_Float16)(rg * hb[r][lane]);
            }
            if (l15 < 8)
                st8v(rbufg16 + (size_t)bcol * DIM + jbase + lgq * 4,
                     __builtin_bit_cast(f32x2, rh4));
        }
        // bar1: rh published / x consumed
        slot_bar(slots1g, bkg, (unsigned)(t + 1), dead);

        // ---- Phase B: candB MFMA over rh (direct sc1, disjoint halves) ----
        if (wv == 4 || wv == 5) {
            const _Float16* rsrc = rbufg16 + (size_t)bcol * DIM + ((wv == 5) ? 512 : 0);
            f32x4 rraw[16];
            #pragma unroll
            for (int kc = 0; kc < 16; ++kc)
                ld4v(rraw[kc], (const float*)(rsrc + kc * 32 + lgq * 8));
            vmwait0();
            #pragma unroll
            for (int kc = 0; kc < 16; ++kc)
                asm volatile("" : "+v"(rraw[kc]));
            f32x4 acc = {0.f, 0.f, 0.f, 0.f};
            #pragma unroll
            for (int kc = 0; kc < 16; ++kc)
                acc = __builtin_amdgcn_mfma_f32_16x16x32_f16(
                    Wb[kc], __builtin_bit_cast(h8f, rraw[kc]), acc, 0, 0, 0);
            #pragma unroll
            for (int r = 0; r < 4; ++r) pcb[wv - 4][r][lane] = acc[r];
        }
        __syncthreads();   // S2: candB partials ready

        // ---- update (w6): cand = tanh(cA+cB+b), h = z*h + (1-z)*cand ----
        if (wv == 6) {
            h4f hp; u16x4 yp;
            #pragma unroll
            for (int r = 0; r < 4; ++r) {
                const float cand = tanhf(pc[0][r][lane] + pc[1][r][lane]
                                         + pcb[0][r][lane] + pcb[1][r][lane] + cb4[r]);
                const float hn = zreg[r] * hold[r] + (1.f - zreg[r]) * cand;
                hold[r] = hn;
                hb[r][lane] = hn;
                hp[r] = (_Float16)hn;
                union { __hip_bfloat16 b; unsigned short u; } cv;
                cv.b = __float2bfloat16(hn);
                yp[r] = cv.u;
            }
            if (l15 < 8) {
                st8v(hdst16 + (size_t)bcol * DIM + jbase + lgq * 4,
                     __builtin_bit_cast(f32x2, hp));
                if (g == NGROUP - 1)
                    *(f32x2*)(ysfb + ((size_t)bcol * SEQ + t) * DIM + jbase + lgq * 4) =
                        __builtin_bit_cast(f32x2, yp);
            }
        }
        // bar2: h(t) published
        slot_bar(slots2g, bkg, (unsigned)(t + 2), dead);
    }

    if (dead && tid == 0) {
        union { __hip_bfloat16 b; unsigned short u; } cv;
        cv.b = __float2bfloat16(1.0e8f);
        ((unsigned short*)ysfb)[blockIdx.x] = cv.u;   // unmistakable sentinel
    }
}

// ---------------------------------------------------------------------------
// Logits GEMM: C[m][n] = sum_k ys[m][k] * outW[n][k]
// A bf16 direct into LDS; B fp32 converted during staging.
// ---------------------------------------------------------------------------
#define BM 128
#define BN 128
#define BK 64

__global__ void __launch_bounds__(256) out_gemm(
    const __hip_bfloat16* __restrict__ A,   // [4096][1024] bf16
    const float* __restrict__ B,            // [32000][1024] fp32
    float* __restrict__ C)                  // [4096][32000]
{
    __shared__ __hip_bfloat16 At[BM][BK + 8];
    __shared__ __hip_bfloat16 Bt[BN][BK + 8];

    const int tid  = threadIdx.x;
    const int lane = tid & 63;
    const int wv   = tid >> 6;
    const int wm   = wv >> 1, wn = wv & 1;
    const int m0   = blockIdx.y * BM;
    const int n0   = blockIdx.x * BN;

    f32x4 acc[4][4];
    #pragma unroll
    for (int i = 0; i < 4; ++i)
        #pragma unroll
        for (int jj = 0; jj < 4; ++jj)
            acc[i][jj] = (f32x4){0.f, 0.f, 0.f, 0.f};

    const int srow = tid >> 3;           // 0..31
    const int scol = (tid & 7) * 8;      // 0..56
    const int l15  = lane & 15;
    const int l4   = lane >> 4;

    for (int kt = 0; kt < DIM / BK; ++kt) {
        const int k0 = kt * BK;
        #pragma unroll
        for (int rnd = 0; rnd < 4; ++rnd) {
            const int row = rnd * 32 + srow;
            *(u16x8*)&At[row][scol] =
                *(const u16x8*)&A[(size_t)(m0 + row) * DIM + k0 + scol];
            *(u16x8*)&Bt[row][scol] =
                cvt8_bf16(&B[(size_t)(n0 + row) * DIM + k0 + scol]);
        }
        __syncthreads();
        #pragma unroll
        for (int ks = 0; ks < 2; ++ks) {
            bf16x8 av[4], bv[4];
            #pragma unroll
            for (int i = 0; i < 4; ++i) {
                av[i] = *(const bf16x8*)&At[wm * 64 + i * 16 + l15][ks * 32 + l4 * 8];
                bv[i] = *(const bf16x8*)&Bt[wn * 64 + i * 16 + l15][ks * 32 + l4 * 8];
            }
            #pragma unroll
            for (int i = 0; i < 4; ++i)
                #pragma unroll
                for (int jj = 0; jj < 4; ++jj)
                    acc[i][jj] = __builtin_amdgcn_mfma_f32_16x16x32_bf16(
                        av[i], bv[jj], acc[i][jj], 0, 0, 0);
        }
        __syncthreads();
    }

    const int rq = l4 * 4;
    #pragma unroll
    for (int i = 0; i < 4; ++i) {
        const int rbase = m0 + wm * 64 + i * 16 + rq;
        #pragma unroll
        for (int jj = 0; jj < 4; ++jj) {
            const int col = n0 + wn * 64 + jj * 16 + l15;
            #pragma unroll
            for (int r2 = 0; r2 < 4; ++r2)
                C[(size_t)(rbase + r2) * VOCAB + col] = acc[i][jj][r2];
        }
    }
}

// ---------------------------------------------------------------------------
extern "C" void kernel_launch(void* const* d_in, const int* in_sizes, int n_in,
                              void* d_out, int out_size, void* d_ws, size_t ws_size,
                              hipStream_t stream)
{
    (void)in_sizes; (void)n_in; (void)out_size; (void)ws_size;
    const int*   ids  = (const int*)  d_in[0];
    const float* embW = (const float*)d_in[1];
    const float* hst  = (const float*)d_in[2];
    const float* gW   = (const float*)d_in[3];
    const float* gB   = (const float*)d_in[4];
    const float* cW   = (const float*)d_in[5];
    const float* cB   = (const float*)d_in[6];
    const float* outW = (const float*)d_in[7];
    float* logits = (float*)d_out;

    // workspace carve-up (~8.7 MiB)
    char* ws = (char*)d_ws;
    unsigned*       bar    = (unsigned*)ws;                       // 16 KiB
    _Float16*       rbuf16 = (_Float16*)(ws + 16384);             // 64 KiB
    _Float16*       hbuf16 = (_Float16*)(ws + 16384 + 65536);     // 256 KiB
    __hip_bfloat16* ysfb   = (__hip_bfloat16*)(ws + 16384 + 65536 + 262144);  // 8 MiB

    // 1) zero slot arrays
    bar_init_kernel<<<dim3(1), dim3(1024), 0, stream>>>(bar);

    // 2) GRU scan (LDS-staged x, direct h/rh, fp16 exchanges)
    gru_scan<<<dim3(SCAN_BLOCKS), dim3(SCAN_THREADS), 0, stream>>>(
        ids, embW, hst, gW, gB, cW, cB, hbuf16, rbuf16, ysfb, bar);

    // 3) logits GEMM (bf16 A, fp32 B)
    out_gemm<<<dim3(VOCAB / BN, (NB * SEQ) / BM), dim3(256), 0, stream>>>(ysfb, outW, logits);
}

// Round 16
// 3694.366 us; speedup vs baseline: 1.8263x; 1.7234x over previous
//
#include <hip/hip_runtime.h>
#include <hip/hip_bf16.h>

#define VOCAB  32000
#define DIM    1024
#define NLAYER 4
#define NB     8
#define SEQ    512

#define NGROUP       4
#define GBLKS        64
#define SCAN_BLOCKS  (NGROUP * GBLKS)      // 256
#define SCAN_THREADS 512                   // 8 waves, role-split
#define ROWH         2056                  // act row stride (2048 + 8 pad halves)

typedef __attribute__((ext_vector_type(8))) short          bf16x8;
typedef __attribute__((ext_vector_type(4))) float          f32x4;
typedef __attribute__((ext_vector_type(2))) float          f32x2;
typedef __attribute__((ext_vector_type(8))) unsigned short u16x8;
typedef __attribute__((ext_vector_type(4))) unsigned short u16x4;
typedef __attribute__((ext_vector_type(8))) _Float16       h8f;
typedef __attribute__((ext_vector_type(4))) _Float16       h4f;

__device__ __forceinline__ u16x8 cvt8_bf16(const float* p) {
    float4 f0 = *(const float4*)p;
    float4 f1 = *(const float4*)(p + 4);
    union { __hip_bfloat16 h[8]; u16x8 v; } u;
    u.h[0] = __float2bfloat16(f0.x); u.h[1] = __float2bfloat16(f0.y);
    u.h[2] = __float2bfloat16(f0.z); u.h[3] = __float2bfloat16(f0.w);
    u.h[4] = __float2bfloat16(f1.x); u.h[5] = __float2bfloat16(f1.y);
    u.h[6] = __float2bfloat16(f1.z); u.h[7] = __float2bfloat16(f1.w);
    return u.v;
}

__device__ __forceinline__ h8f pack8(f32x4 a, f32x4 b) {
    h8f o;
    o[0] = (_Float16)a[0]; o[1] = (_Float16)a[1];
    o[2] = (_Float16)a[2]; o[3] = (_Float16)a[3];
    o[4] = (_Float16)b[0]; o[5] = (_Float16)b[1];
    o[6] = (_Float16)b[2]; o[7] = (_Float16)b[3];
    return o;
}

// ---- coherence-point (L3) accesses: bypass per-XCD L2 (no cache fences) ----
__device__ __forceinline__ void ld4v(f32x4& d, const float* p) {
    asm volatile("global_load_dwordx4 %0, %1, off sc0 sc1"
                 : "=&v"(d) : "v"(p));
}
__device__ __forceinline__ void st8v(void* p, f32x2 v) {
    asm volatile("global_store_dwordx2 %0, %1, off sc0 sc1"
                 :: "v"(p), "v"(v) : "memory");
}
__device__ __forceinline__ void st2v(void* p, unsigned v) {
    asm volatile("global_store_short %0, %1, off sc0 sc1"
                 :: "v"(p), "v"(v) : "memory");
}
__device__ __forceinline__ void vmwait0() {
    asm volatile("s_waitcnt vmcnt(0)" ::: "memory");
}

// ---------------------------------------------------------------------------
__global__ void bar_init_kernel(unsigned* __restrict__ bar) {
    bar[threadIdx.x]        = 0u;
    bar[threadIdx.x + 1024] = 0u;
    bar[threadIdx.x + 2048] = 0u;
    bar[threadIdx.x + 3072] = 0u;   // 4096 words = 16 KiB
}

// ---------------------------------------------------------------------------
// Fence-free slot barrier (round-12 form — proven best).
// ---------------------------------------------------------------------------
__device__ __forceinline__ void slot_bar(unsigned* __restrict__ slots, int bkg,
                                         unsigned seq, bool& dead) {
    __syncthreads();
    const int tid = threadIdx.x;
    if (tid == 0)
        __hip_atomic_store(&slots[bkg * 8], seq, __ATOMIC_RELAXED,
                           __HIP_MEMORY_SCOPE_AGENT);
    if (tid < 64 && !dead) {
        unsigned guard = 0;
        for (;;) {
            unsigned v = __hip_atomic_load(&slots[tid * 8], __ATOMIC_RELAXED,
                                           __HIP_MEMORY_SCOPE_AGENT);
            if (__all((int)(v >= seq))) break;
            __builtin_amdgcn_s_sleep(1);
            if (++guard > (1u << 16)) { dead = true; break; }
        }
    }
    __syncthreads();
}

// ---------------------------------------------------------------------------
// MFMA layer-pipelined persistent-weight GRU scan — round-12 structure
// (all MFMA B-operands from LDS) + fp16 exchanges + producer-side rh.
// Wave roles: w0-3 z+r K-quarters over [x|h]; w4-5 candA x-halves (A) /
// candB rh-halves (B); w6 z-combine + update; w7 r-combine -> rh publish.
// ---------------------------------------------------------------------------
__global__ void __launch_bounds__(SCAN_THREADS)
__attribute__((amdgpu_waves_per_eu(2, 2)))
gru_scan(
    const int*   __restrict__ ids,     // [NB][SEQ]
    const float* __restrict__ embW,    // [VOCAB][DIM] fp32
    const float* __restrict__ hstart,  // [NLAYER][DIM]
    const float* __restrict__ gW,      // [NLAYER][2*DIM][2*DIM]
    const float* __restrict__ gB,      // [NLAYER][2*DIM]
    const float* __restrict__ cW,      // [NLAYER][DIM][2*DIM]
    const float* __restrict__ cB,      // [NLAYER][DIM]
    _Float16* __restrict__ hbuf16,     // [4][NLAYER][NB][DIM] fp16 ring
    _Float16* __restrict__ rbuf16,     // [NGROUP][NB][DIM] fp16 (rh)
    __hip_bfloat16* __restrict__ ysfb, // [NB][SEQ][DIM] bf16
    unsigned* __restrict__ bar)
{
    __shared__ _Float16 act[NB][ROWH];     // 32,896 B: x [0,1024) | h [1024,2048)
    __shared__ float pz[4][4][64];
    __shared__ float pr[4][4][64];
    __shared__ float pc[2][4][64];
    __shared__ float pcb[2][4][64];
    __shared__ float hb[4][64];            // h(t-1) handoff w6 -> w7

    const int tid   = threadIdx.x;
    const int lane  = tid & 63;
    const int wv    = tid >> 6;               // 0..7
    const int l15   = lane & 15;
    const int lgq   = lane >> 4;              // 0..3
    const int bcol  = l15 & 7;                // batch (cols 8..15 dup 0..7)
    const int g     = blockIdx.x >> 6;        // layer group
    const int bkg   = blockIdx.x & (GBLKS-1);
    const int jbase = bkg * 16;
    const int jrow  = jbase + l15;            // this lane's A row

    // ---- persistent fp16 A-fragment weights (pinned; unified VGPR/AGPR) ----
    h8f Wa[16], Wb[16];
    if (wv < 6) {
        const float* wzp = gW + ((size_t)g * 2048 + jrow) * 2048;
        const float* wrp = gW + ((size_t)g * 2048 + 1024 + jrow) * 2048;
        const float* wcp = cW + ((size_t)g * 1024 + jrow) * 2048;
        const float* baseA; const float* baseB; int koA, koB;
        switch (wv) {
          case 0:  baseA = wzp; koA = 0;    baseB = wrp; koB = 0;    break;
          case 1:  baseA = wzp; koA = 512;  baseB = wrp; koB = 512;  break;
          case 2:  baseA = wzp; koA = 1024; baseB = wrp; koB = 1024; break;
          case 3:  baseA = wzp; koA = 1536; baseB = wrp; koB = 1536; break;
          case 4:  baseA = wcp; koA = 0;    baseB = wcp; koB = 1024; break;
          default: baseA = wcp; koA = 512;  baseB = wcp; koB = 1536; break;
        }
        #pragma unroll
        for (int kc = 0; kc < 16; ++kc) {
            const int ka = koA + kc * 32 + lgq * 8;
            const int kb = koB + kc * 32 + lgq * 8;
            Wa[kc] = pack8(*(const f32x4*)(baseA + ka), *(const f32x4*)(baseA + ka + 4));
            Wb[kc] = pack8(*(const f32x4*)(baseB + kb), *(const f32x4*)(baseB + kb + 4));
        }
        #pragma unroll
        for (int kc = 0; kc < 16; ++kc) {
            asm volatile("" : "+v"(Wa[kc]));
            asm volatile("" : "+v"(Wb[kc]));
        }
    }

    float bz4[4], br4[4], cb4[4], hold[4], zreg[4];
    if (wv == 6) {
        #pragma unroll
        for (int r = 0; r < 4; ++r) {
            const int j = jbase + lgq * 4 + r;
            bz4[r]  = gB[g * 2048 + j];
            cb4[r]  = cB[g * 1024 + j];
            hold[r] = hstart[g * 1024 + j];
            hb[r][lane] = hold[r];
        }
    }
    if (wv == 7) {
        #pragma unroll
        for (int r = 0; r < 4; ++r)
            br4[r] = gB[g * 2048 + 1024 + jbase + lgq * 4 + r];
    }

    bool dead = false;
    unsigned* slots1g = bar + g * 512;
    unsigned* slots2g = bar + 2048 + g * 512;
    unsigned* s2prev  = (g > 0)          ? bar + 2048 + (g - 1) * 512 : nullptr;
    unsigned* s1next  = (g < NGROUP - 1) ? bar + (g + 1) * 512        : nullptr;
    _Float16* rbufg16 = rbuf16 + (size_t)g * NB * DIM;

    // init own layer h(-1) into ring slot 3 (fp16, sc1)
    if (tid < 128) {
        int e = bkg * 128 + tid;   // 0..8191 over [NB][DIM]
        union { _Float16 h; unsigned short u; } cv;
        cv.h = (_Float16)hstart[g * DIM + (e & (DIM - 1))];
        st2v(&hbuf16[((size_t)3 * NLAYER + g) * NB * DIM + e], (unsigned)cv.u);
    }
    slot_bar(slots2g, bkg, 1u, dead);

    for (int t = 0; t < SEQ; ++t) {
        const int so = (t + 3) & 3;   // h_old slot
        const int sw = t & 3;         // h_new slot
        const _Float16* hsrc16  = hbuf16 + ((size_t)so * NLAYER + g) * NB * DIM;
        _Float16*       hdst16  = hbuf16 + ((size_t)sw * NLAYER + g) * NB * DIM;
        const _Float16* xprev16 = hbuf16 + ((size_t)sw * NLAYER + (g > 0 ? g - 1 : 0)) * NB * DIM;

        // ---- peer gates (round-12 combined form) ----
        {
            const unsigned need_a = (g > 0) ? (unsigned)(t + 2) : 0u;
            const unsigned need_b = (g < NGROUP - 1 && t >= 4) ? (unsigned)(t - 3) : 0u;
            if (tid < 64 && !dead && (need_a | need_b)) {
                unsigned guard = 0;
                for (;;) {
                    bool ok = true;
                    if (need_a)
                        ok &= (__hip_atomic_load(&s2prev[tid * 8], __ATOMIC_RELAXED,
                                                 __HIP_MEMORY_SCOPE_AGENT) >= need_a);
                    if (need_b)
                        ok &= (__hip_atomic_load(&s1next[tid * 8], __ATOMIC_RELAXED,
                                                 __HIP_MEMORY_SCOPE_AGENT) >= need_b);
                    if (__all((int)ok)) break;
                    __builtin_amdgcn_s_sleep(1);
                    if (++guard > (1u << 16)) { dead = true; break; }
                }
            }
            __syncthreads();
        }

        // ---- stage x -> act[.][0:1024) and h_old -> act[.][1024:2048) ----
        if (g == 0) {
            #pragma unroll
            for (int q = 0; q < 2; ++q) {
                const int u = q * SCAN_THREADS + tid;   // 0..1023
                const int b = u >> 7, d8 = (u & 127) * 8;
                const float* p = embW + (size_t)ids[b * SEQ + t] * DIM + d8;
                *(h8f*)&act[b][d8] = pack8(*(const f32x4*)p, *(const f32x4*)(p + 4));
            }
            f32x4 hv[2];
            #pragma unroll
            for (int q = 0; q < 2; ++q) {
                const int u = q * SCAN_THREADS + tid;
                ld4v(hv[q], (const float*)(hsrc16 + (size_t)(u >> 7) * DIM + (u & 127) * 8));
            }
            vmwait0();
            asm volatile("" : "+v"(hv[0]), "+v"(hv[1]));
            #pragma unroll
            for (int q = 0; q < 2; ++q) {
                const int u = q * SCAN_THREADS + tid;
                *(h8f*)&act[u >> 7][1024 + (u & 127) * 8] = __builtin_bit_cast(h8f, hv[q]);
            }
        } else {
            f32x4 xv[2], hv[2];
            #pragma unroll
            for (int q = 0; q < 2; ++q) {
                const int u = q * SCAN_THREADS + tid;
                ld4v(xv[q], (const float*)(xprev16 + (size_t)(u >> 7) * DIM + (u & 127) * 8));
                ld4v(hv[q], (const float*)(hsrc16 + (size_t)(u >> 7) * DIM + (u & 127) * 8));
            }
            vmwait0();
            asm volatile("" : "+v"(xv[0]), "+v"(xv[1]), "+v"(hv[0]), "+v"(hv[1]));
            #pragma unroll
            for (int q = 0; q < 2; ++q) {
                const int u = q * SCAN_THREADS + tid;
                const int b = u >> 7, d8 = (u & 127) * 8;
                *(h8f*)&act[b][d8]        = __builtin_bit_cast(h8f, xv[q]);
                *(h8f*)&act[b][1024 + d8] = __builtin_bit_cast(h8f, hv[q]);
            }
        }
        __syncthreads();   // S0: act staged

        // ---- Phase A: MFMA dots (B-operands from LDS) ----
        if (wv < 6) {
            const int kb2 = (wv < 4) ? wv * 512 : (wv - 4) * 512;
            f32x4 accA = {0.f, 0.f, 0.f, 0.f};
            f32x4 accB = {0.f, 0.f, 0.f, 0.f};
            #pragma unroll
            for (int kc = 0; kc < 16; ++kc) {
                const h8f bf = *(const h8f*)&act[bcol][kb2 + kc * 32 + lgq * 8];
                accA = __builtin_amdgcn_mfma_f32_16x16x32_f16(Wa[kc], bf, accA, 0, 0, 0);
                if (wv < 4)
                    accB = __builtin_amdgcn_mfma_f32_16x16x32_f16(Wb[kc], bf, accB, 0, 0, 0);
            }
            if (wv < 4) {
                #pragma unroll
                for (int r = 0; r < 4; ++r) {
                    pz[wv][r][lane] = accA[r];
                    pr[wv][r][lane] = accB[r];
                }
            } else {
                #pragma unroll
                for (int r = 0; r < 4; ++r) pc[wv - 4][r][lane] = accA[r];
            }
        }
        __syncthreads();   // S1: partials ready

        // ---- combine: z (w6, regs) ; r -> rh publish (w7, fp16 sc1) ----
        if (wv == 6) {
            #pragma unroll
            for (int r = 0; r < 4; ++r) {
                const float s = pz[0][r][lane] + pz[1][r][lane]
                              + pz[2][r][lane] + pz[3][r][lane] + bz4[r];
                zreg[r] = 1.f / (1.f + expf(-s));
            }
        }
        if (wv == 7) {
            h4f rh4;
            #pragma unroll
            for (int r = 0; r < 4; ++r) {
                const float s = pr[0][r][lane] + pr[1][r][lane]
                              + pr[2][r][lane] + pr[3][r][lane] + br4[r];
                const float rg = 1.f / (1.f + expf(-s));
                rh4[r] = (_Float16)(rg * hb[r][lane]);
            }
            if (l15 < 8)
                st8v(rbufg16 + (size_t)bcol * DIM + jbase + lgq * 4,
                     __builtin_bit_cast(f32x2, rh4));
        }
        // bar1: rh published / x consumed
        slot_bar(slots1g, bkg, (unsigned)(t + 1), dead);

        // ---- stage rh -> act x-half (pure copy, fp16) ----
        {
            f32x4 rv[2];
            #pragma unroll
            for (int q = 0; q < 2; ++q) {
                const int u = q * SCAN_THREADS + tid;
                ld4v(rv[q], (const float*)(rbufg16 + (size_t)(u >> 7) * DIM + (u & 127) * 8));
            }
            vmwait0();
            asm volatile("" : "+v"(rv[0]), "+v"(rv[1]));
            #pragma unroll
            for (int q = 0; q < 2; ++q) {
                const int u = q * SCAN_THREADS + tid;
                *(h8f*)&act[u >> 7][(u & 127) * 8] = __builtin_bit_cast(h8f, rv[q]);
            }
        }
        __syncthreads();

        // ---- Phase B: candB MFMA over rh (from LDS) ----
        if (wv == 4 || wv == 5) {
            const int kb2 = (wv - 4) * 512;
            f32x4 acc = {0.f, 0.f, 0.f, 0.f};
            #pragma unroll
            for (int kc = 0; kc < 16; ++kc) {
                const h8f bf = *(const h8f*)&act[bcol][kb2 + kc * 32 + lgq * 8];
                acc = __builtin_amdgcn_mfma_f32_16x16x32_f16(Wb[kc], bf, acc, 0, 0, 0);
            }
            #pragma unroll
            for (int r = 0; r < 4; ++r) pcb[wv - 4][r][lane] = acc[r];
        }
        __syncthreads();   // S2: candB partials ready

        // ---- update (w6): cand = tanh(cA+cB+b), h = z*h + (1-z)*cand ----
        if (wv == 6) {
            h4f hp; u16x4 yp;
            #pragma unroll
            for (int r = 0; r < 4; ++r) {
                const float cand = tanhf(pc[0][r][lane] + pc[1][r][lane]
                                         + pcb[0][r][lane] + pcb[1][r][lane] + cb4[r]);
                const float hn = zreg[r] * hold[r] + (1.f - zreg[r]) * cand;
                hold[r] = hn;
                hb[r][lane] = hn;
                hp[r] = (_Float16)hn;
                union { __hip_bfloat16 b; unsigned short u; } cv;
                cv.b = __float2bfloat16(hn);
                yp[r] = cv.u;
            }
            if (l15 < 8) {
                st8v(hdst16 + (size_t)bcol * DIM + jbase + lgq * 4,
                     __builtin_bit_cast(f32x2, hp));
                if (g == NGROUP - 1)
                    *(f32x2*)(ysfb + ((size_t)bcol * SEQ + t) * DIM + jbase + lgq * 4) =
                        __builtin_bit_cast(f32x2, yp);
            }
        }
        // bar2: h(t) published
        slot_bar(slots2g, bkg, (unsigned)(t + 2), dead);
    }

    if (dead && tid == 0) {
        union { __hip_bfloat16 b; unsigned short u; } cv;
        cv.b = __float2bfloat16(1.0e8f);
        ((unsigned short*)ysfb)[blockIdx.x] = cv.u;   // unmistakable sentinel
    }
}

// ---------------------------------------------------------------------------
// Logits GEMM: C[m][n] = sum_k ys[m][k] * outW[n][k]
// A bf16 direct into LDS; B fp32 converted during staging.
// ---------------------------------------------------------------------------
#define BM 128
#define BN 128
#define BK 64

__global__ void __launch_bounds__(256) out_gemm(
    const __hip_bfloat16* __restrict__ A,   // [4096][1024] bf16
    const float* __restrict__ B,            // [32000][1024] fp32
    float* __restrict__ C)                  // [4096][32000]
{
    __shared__ __hip_bfloat16 At[BM][BK + 8];
    __shared__ __hip_bfloat16 Bt[BN][BK + 8];

    const int tid  = threadIdx.x;
    const int lane = tid & 63;
    const int wv   = tid >> 6;
    const int wm   = wv >> 1, wn = wv & 1;
    const int m0   = blockIdx.y * BM;
    const int n0   = blockIdx.x * BN;

    f32x4 acc[4][4];
    #pragma unroll
    for (int i = 0; i < 4; ++i)
        #pragma unroll
        for (int jj = 0; jj < 4; ++jj)
            acc[i][jj] = (f32x4){0.f, 0.f, 0.f, 0.f};

    const int srow = tid >> 3;           // 0..31
    const int scol = (tid & 7) * 8;      // 0..56
    const int l15  = lane & 15;
    const int l4   = lane >> 4;

    for (int kt = 0; kt < DIM / BK; ++kt) {
        const int k0 = kt * BK;
        #pragma unroll
        for (int rnd = 0; rnd < 4; ++rnd) {
            const int row = rnd * 32 + srow;
            *(u16x8*)&At[row][scol] =
                *(const u16x8*)&A[(size_t)(m0 + row) * DIM + k0 + scol];
            *(u16x8*)&Bt[row][scol] =
                cvt8_bf16(&B[(size_t)(n0 + row) * DIM + k0 + scol]);
        }
        __syncthreads();
        #pragma unroll
        for (int ks = 0; ks < 2; ++ks) {
            bf16x8 av[4], bv[4];
            #pragma unroll
            for (int i = 0; i < 4; ++i) {
                av[i] = *(const bf16x8*)&At[wm * 64 + i * 16 + l15][ks * 32 + l4 * 8];
                bv[i] = *(const bf16x8*)&Bt[wn * 64 + i * 16 + l15][ks * 32 + l4 * 8];
            }
            #pragma unroll
            for (int i = 0; i < 4; ++i)
                #pragma unroll
                for (int jj = 0; jj < 4; ++jj)
                    acc[i][jj] = __builtin_amdgcn_mfma_f32_16x16x32_bf16(
                        av[i], bv[jj], acc[i][jj], 0, 0, 0);
        }
        __syncthreads();
    }

    const int rq = l4 * 4;
    #pragma unroll
    for (int i = 0; i < 4; ++i) {
        const int rbase = m0 + wm * 64 + i * 16 + rq;
        #pragma unroll
        for (int jj = 0; jj < 4; ++jj) {
            const int col = n0 + wn * 64 + jj * 16 + l15;
            #pragma unroll
            for (int r2 = 0; r2 < 4; ++r2)
                C[(size_t)(rbase + r2) * VOCAB + col] = acc[i][jj][r2];
        }
    }
}

// ---------------------------------------------------------------------------
extern "C" void kernel_launch(void* const* d_in, const int* in_sizes, int n_in,
                              void* d_out, int out_size, void* d_ws, size_t ws_size,
                              hipStream_t stream)
{
    (void)in_sizes; (void)n_in; (void)out_size; (void)ws_size;
    const int*   ids  = (const int*)  d_in[0];
    const float* embW = (const float*)d_in[1];
    const float* hst  = (const float*)d_in[2];
    const float* gW   = (const float*)d_in[3];
    const float* gB   = (const float*)d_in[4];
    const float* cW   = (const float*)d_in[5];
    const float* cB   = (const float*)d_in[6];
    const float* outW = (const float*)d_in[7];
    float* logits = (float*)d_out;

    // workspace carve-up (~8.7 MiB)
    char* ws = (char*)d_ws;
    unsigned*       bar    = (unsigned*)ws;                       // 16 KiB
    _Float16*       rbuf16 = (_Float16*)(ws + 16384);             // 64 KiB
    _Float16*       hbuf16 = (_Float16*)(ws + 16384 + 65536);     // 256 KiB
    __hip_bfloat16* ysfb   = (__hip_bfloat16*)(ws + 16384 + 65536 + 262144);  // 8 MiB

    // 1) zero slot arrays
    bar_init_kernel<<<dim3(1), dim3(1024), 0, stream>>>(bar);

    // 2) GRU scan (r12 structure, fp16 exchanges, producer-side rh)
    gru_scan<<<dim3(SCAN_BLOCKS), dim3(SCAN_THREADS), 0, stream>>>(
        ids, embW, hst, gW, gB, cW, cB, hbuf16, rbuf16, ysfb, bar);

    // 3) logits GEMM (bf16 A, fp32 B)
    out_gemm<<<dim3(VOCAB / BN, (NB * SEQ) / BM), dim3(256), 0, stream>>>(ysfb, outW, logits);
}

// Round 17
// 3503.913 us; speedup vs baseline: 1.9256x; 1.0544x over previous
//
#include <hip/hip_runtime.h>
#include <hip/hip_bf16.h>

#define VOCAB  32000
#define DIM    1024
#define NLAYER 4
#define NB     8
#define SEQ    512

#define NGROUP       4
#define GBLKS        64
#define SCAN_BLOCKS  (NGROUP * GBLKS)      // 256
#define SCAN_THREADS 512                   // 8 waves, role-split
#define ROWH         2056                  // act row stride (2048 + 8 pad halves)

typedef __attribute__((ext_vector_type(8))) short          bf16x8;
typedef __attribute__((ext_vector_type(4))) float          f32x4;
typedef __attribute__((ext_vector_type(2))) float          f32x2;
typedef __attribute__((ext_vector_type(8))) unsigned short u16x8;
typedef __attribute__((ext_vector_type(4))) unsigned short u16x4;
typedef __attribute__((ext_vector_type(8))) _Float16       h8f;
typedef __attribute__((ext_vector_type(4))) _Float16       h4f;

__device__ __forceinline__ u16x8 cvt8_bf16(const float* p) {
    float4 f0 = *(const float4*)p;
    float4 f1 = *(const float4*)(p + 4);
    union { __hip_bfloat16 h[8]; u16x8 v; } u;
    u.h[0] = __float2bfloat16(f0.x); u.h[1] = __float2bfloat16(f0.y);
    u.h[2] = __float2bfloat16(f0.z); u.h[3] = __float2bfloat16(f0.w);
    u.h[4] = __float2bfloat16(f1.x); u.h[5] = __float2bfloat16(f1.y);
    u.h[6] = __float2bfloat16(f1.z); u.h[7] = __float2bfloat16(f1.w);
    return u.v;
}

__device__ __forceinline__ h8f pack8(f32x4 a, f32x4 b) {
    h8f o;
    o[0] = (_Float16)a[0]; o[1] = (_Float16)a[1];
    o[2] = (_Float16)a[2]; o[3] = (_Float16)a[3];
    o[4] = (_Float16)b[0]; o[5] = (_Float16)b[1];
    o[6] = (_Float16)b[2]; o[7] = (_Float16)b[3];
    return o;
}

// ---- coherence-point (L3) accesses: bypass per-XCD L2 (no cache fences) ----
__device__ __forceinline__ void ld4v(f32x4& d, const float* p) {
    asm volatile("global_load_dwordx4 %0, %1, off sc0 sc1"
                 : "=&v"(d) : "v"(p));
}
__device__ __forceinline__ void st8v(void* p, f32x2 v) {
    asm volatile("global_store_dwordx2 %0, %1, off sc0 sc1"
                 :: "v"(p), "v"(v) : "memory");
}
__device__ __forceinline__ void st2v(void* p, unsigned v) {
    asm volatile("global_store_short %0, %1, off sc0 sc1"
                 :: "v"(p), "v"(v) : "memory");
}
__device__ __forceinline__ void vmwait0() {
    asm volatile("s_waitcnt vmcnt(0)" ::: "memory");
}

// ---------------------------------------------------------------------------
__global__ void bar_init_kernel(unsigned* __restrict__ bar) {
    bar[threadIdx.x]        = 0u;
    bar[threadIdx.x + 1024] = 0u;
    bar[threadIdx.x + 2048] = 0u;
    bar[threadIdx.x + 3072] = 0u;   // 4096 words = 16 KiB
}

// ---------------------------------------------------------------------------
// Fence-free slot barrier (round-12 form — proven best).
// ---------------------------------------------------------------------------
__device__ __forceinline__ void slot_bar(unsigned* __restrict__ slots, int bkg,
                                         unsigned seq, bool& dead) {
    __syncthreads();
    const int tid = threadIdx.x;
    if (tid == 0)
        __hip_atomic_store(&slots[bkg * 8], seq, __ATOMIC_RELAXED,
                           __HIP_MEMORY_SCOPE_AGENT);
    if (tid < 64 && !dead) {
        unsigned guard = 0;
        for (;;) {
            unsigned v = __hip_atomic_load(&slots[tid * 8], __ATOMIC_RELAXED,
                                           __HIP_MEMORY_SCOPE_AGENT);
            if (__all((int)(v >= seq))) break;
            __builtin_amdgcn_s_sleep(1);
            if (++guard > (1u << 16)) { dead = true; break; }
        }
    }
    __syncthreads();
}

// ---------------------------------------------------------------------------
// MFMA layer-pipelined persistent-weight GRU scan — round-16 structure.
// NEW: groups 1-3 (pipeline-idle at startup) convert out_W fp32 -> bf16 into
// ws before entering the scan loop (doConv gate), hiding the conversion in
// the pipeline-fill window. Everything else byte-identical to round 16.
// ---------------------------------------------------------------------------
__global__ void __launch_bounds__(SCAN_THREADS)
__attribute__((amdgpu_waves_per_eu(2, 2)))
gru_scan(
    const int*   __restrict__ ids,     // [NB][SEQ]
    const float* __restrict__ embW,    // [VOCAB][DIM] fp32
    const float* __restrict__ hstart,  // [NLAYER][DIM]
    const float* __restrict__ gW,      // [NLAYER][2*DIM][2*DIM]
    const float* __restrict__ gB,      // [NLAYER][2*DIM]
    const float* __restrict__ cW,      // [NLAYER][DIM][2*DIM]
    const float* __restrict__ cB,      // [NLAYER][DIM]
    _Float16* __restrict__ hbuf16,     // [4][NLAYER][NB][DIM] fp16 ring
    _Float16* __restrict__ rbuf16,     // [NGROUP][NB][DIM] fp16 (rh)
    __hip_bfloat16* __restrict__ ysfb, // [NB][SEQ][DIM] bf16
    unsigned* __restrict__ bar,
    const float* __restrict__ outW,    // [VOCAB][DIM] fp32
    __hip_bfloat16* __restrict__ outWb,// [VOCAB][DIM] bf16 (ws) or null
    int doConv)
{
    __shared__ _Float16 act[NB][ROWH];     // 32,896 B: x [0,1024) | h [1024,2048)
    __shared__ float pz[4][4][64];
    __shared__ float pr[4][4][64];
    __shared__ float pc[2][4][64];
    __shared__ float pcb[2][4][64];
    __shared__ float hb[4][64];            // h(t-1) handoff w6 -> w7

    const int tid   = threadIdx.x;
    const int lane  = tid & 63;
    const int wv    = tid >> 6;               // 0..7
    const int l15   = lane & 15;
    const int lgq   = lane >> 4;              // 0..3
    const int bcol  = l15 & 7;                // batch (cols 8..15 dup 0..7)
    const int g     = blockIdx.x >> 6;        // layer group
    const int bkg   = blockIdx.x & (GBLKS-1);
    const int jbase = bkg * 16;
    const int jrow  = jbase + l15;            // this lane's A row

    // ---- out_W conversion by pipeline-idle groups 1-3 (before anything) ----
    if (doConv && g > 0) {
        const int cidx = (blockIdx.x - GBLKS) * SCAN_THREADS + tid;  // 0..98303
        for (int u = cidx; u < VOCAB * DIM / 8; u += (SCAN_BLOCKS - GBLKS) * SCAN_THREADS)
            ((u16x8*)outWb)[u] = cvt8_bf16(outW + (size_t)u * 8);
    }

    // ---- persistent fp16 A-fragment weights (pinned; unified VGPR/AGPR) ----
    h8f Wa[16], Wb[16];
    if (wv < 6) {
        const float* wzp = gW + ((size_t)g * 2048 + jrow) * 2048;
        const float* wrp = gW + ((size_t)g * 2048 + 1024 + jrow) * 2048;
        const float* wcp = cW + ((size_t)g * 1024 + jrow) * 2048;
        const float* baseA; const float* baseB; int koA, koB;
        switch (wv) {
          case 0:  baseA = wzp; koA = 0;    baseB = wrp; koB = 0;    break;
          case 1:  baseA = wzp; koA = 512;  baseB = wrp; koB = 512;  break;
          case 2:  baseA = wzp; koA = 1024; baseB = wrp; koB = 1024; break;
          case 3:  baseA = wzp; koA = 1536; baseB = wrp; koB = 1536; break;
          case 4:  baseA = wcp; koA = 0;    baseB = wcp; koB = 1024; break;
          default: baseA = wcp; koA = 512;  baseB = wcp; koB = 1536; break;
        }
        #pragma unroll
        for (int kc = 0; kc < 16; ++kc) {
            const int ka = koA + kc * 32 + lgq * 8;
            const int kb = koB + kc * 32 + lgq * 8;
            Wa[kc] = pack8(*(const f32x4*)(baseA + ka), *(const f32x4*)(baseA + ka + 4));
            Wb[kc] = pack8(*(const f32x4*)(baseB + kb), *(const f32x4*)(baseB + kb + 4));
        }
        #pragma unroll
        for (int kc = 0; kc < 16; ++kc) {
            asm volatile("" : "+v"(Wa[kc]));
            asm volatile("" : "+v"(Wb[kc]));
        }
    }

    float bz4[4], br4[4], cb4[4], hold[4], zreg[4];
    if (wv == 6) {
        #pragma unroll
        for (int r = 0; r < 4; ++r) {
            const int j = jbase + lgq * 4 + r;
            bz4[r]  = gB[g * 2048 + j];
            cb4[r]  = cB[g * 1024 + j];
            hold[r] = hstart[g * 1024 + j];
            hb[r][lane] = hold[r];
        }
    }
    if (wv == 7) {
        #pragma unroll
        for (int r = 0; r < 4; ++r)
            br4[r] = gB[g * 2048 + 1024 + jbase + lgq * 4 + r];
    }

    bool dead = false;
    unsigned* slots1g = bar + g * 512;
    unsigned* slots2g = bar + 2048 + g * 512;
    unsigned* s2prev  = (g > 0)          ? bar + 2048 + (g - 1) * 512 : nullptr;
    unsigned* s1next  = (g < NGROUP - 1) ? bar + (g + 1) * 512        : nullptr;
    _Float16* rbufg16 = rbuf16 + (size_t)g * NB * DIM;

    // init own layer h(-1) into ring slot 3 (fp16, sc1)
    if (tid < 128) {
        int e = bkg * 128 + tid;   // 0..8191 over [NB][DIM]
        union { _Float16 h; unsigned short u; } cv;
        cv.h = (_Float16)hstart[g * DIM + (e & (DIM - 1))];
        st2v(&hbuf16[((size_t)3 * NLAYER + g) * NB * DIM + e], (unsigned)cv.u);
    }
    slot_bar(slots2g, bkg, 1u, dead);

    for (int t = 0; t < SEQ; ++t) {
        const int so = (t + 3) & 3;   // h_old slot
        const int sw = t & 3;         // h_new slot
        const _Float16* hsrc16  = hbuf16 + ((size_t)so * NLAYER + g) * NB * DIM;
        _Float16*       hdst16  = hbuf16 + ((size_t)sw * NLAYER + g) * NB * DIM;
        const _Float16* xprev16 = hbuf16 + ((size_t)sw * NLAYER + (g > 0 ? g - 1 : 0)) * NB * DIM;

        // ---- peer gates (round-12 combined form) ----
        {
            const unsigned need_a = (g > 0) ? (unsigned)(t + 2) : 0u;
            const unsigned need_b = (g < NGROUP - 1 && t >= 4) ? (unsigned)(t - 3) : 0u;
            if (tid < 64 && !dead && (need_a | need_b)) {
                unsigned guard = 0;
                for (;;) {
                    bool ok = true;
                    if (need_a)
                        ok &= (__hip_atomic_load(&s2prev[tid * 8], __ATOMIC_RELAXED,
                                                 __HIP_MEMORY_SCOPE_AGENT) >= need_a);
                    if (need_b)
                        ok &= (__hip_atomic_load(&s1next[tid * 8], __ATOMIC_RELAXED,
                                                 __HIP_MEMORY_SCOPE_AGENT) >= need_b);
                    if (__all((int)ok)) break;
                    __builtin_amdgcn_s_sleep(1);
                    if (++guard > (1u << 16)) { dead = true; break; }
                }
            }
            __syncthreads();
        }

        // ---- stage x -> act[.][0:1024) and h_old -> act[.][1024:2048) ----
        if (g == 0) {
            #pragma unroll
            for (int q = 0; q < 2; ++q) {
                const int u = q * SCAN_THREADS + tid;   // 0..1023
                const int b = u >> 7, d8 = (u & 127) * 8;
                const float* p = embW + (size_t)ids[b * SEQ + t] * DIM + d8;
                *(h8f*)&act[b][d8] = pack8(*(const f32x4*)p, *(const f32x4*)(p + 4));
            }
            f32x4 hv[2];
            #pragma unroll
            for (int q = 0; q < 2; ++q) {
                const int u = q * SCAN_THREADS + tid;
                ld4v(hv[q], (const float*)(hsrc16 + (size_t)(u >> 7) * DIM + (u & 127) * 8));
            }
            vmwait0();
            asm volatile("" : "+v"(hv[0]), "+v"(hv[1]));
            #pragma unroll
            for (int q = 0; q < 2; ++q) {
                const int u = q * SCAN_THREADS + tid;
                *(h8f*)&act[u >> 7][1024 + (u & 127) * 8] = __builtin_bit_cast(h8f, hv[q]);
            }
        } else {
            f32x4 xv[2], hv[2];
            #pragma unroll
            for (int q = 0; q < 2; ++q) {
                const int u = q * SCAN_THREADS + tid;
                ld4v(xv[q], (const float*)(xprev16 + (size_t)(u >> 7) * DIM + (u & 127) * 8));
                ld4v(hv[q], (const float*)(hsrc16 + (size_t)(u >> 7) * DIM + (u & 127) * 8));
            }
            vmwait0();
            asm volatile("" : "+v"(xv[0]), "+v"(xv[1]), "+v"(hv[0]), "+v"(hv[1]));
            #pragma unroll
            for (int q = 0; q < 2; ++q) {
                const int u = q * SCAN_THREADS + tid;
                const int b = u >> 7, d8 = (u & 127) * 8;
                *(h8f*)&act[b][d8]        = __builtin_bit_cast(h8f, xv[q]);
                *(h8f*)&act[b][1024 + d8] = __builtin_bit_cast(h8f, hv[q]);
            }
        }
        __syncthreads();   // S0: act staged

        // ---- Phase A: MFMA dots (B-operands from LDS) ----
        if (wv < 6) {
            const int kb2 = (wv < 4) ? wv * 512 : (wv - 4) * 512;
            f32x4 accA = {0.f, 0.f, 0.f, 0.f};
            f32x4 accB = {0.f, 0.f, 0.f, 0.f};
            #pragma unroll
            for (int kc = 0; kc < 16; ++kc) {
                const h8f bf = *(const h8f*)&act[bcol][kb2 + kc * 32 + lgq * 8];
                accA = __builtin_amdgcn_mfma_f32_16x16x32_f16(Wa[kc], bf, accA, 0, 0, 0);
                if (wv < 4)
                    accB = __builtin_amdgcn_mfma_f32_16x16x32_f16(Wb[kc], bf, accB, 0, 0, 0);
            }
            if (wv < 4) {
                #pragma unroll
                for (int r = 0; r < 4; ++r) {
                    pz[wv][r][lane] = accA[r];
                    pr[wv][r][lane] = accB[r];
                }
            } else {
                #pragma unroll
                for (int r = 0; r < 4; ++r) pc[wv - 4][r][lane] = accA[r];
            }
        }
        __syncthreads();   // S1: partials ready

        // ---- combine: z (w6, regs) ; r -> rh publish (w7, fp16 sc1) ----
        if (wv == 6) {
            #pragma unroll
            for (int r = 0; r < 4; ++r) {
                const float s = pz[0][r][lane] + pz[1][r][lane]
                              + pz[2][r][lane] + pz[3][r][lane] + bz4[r];
                zreg[r] = 1.f / (1.f + expf(-s));
            }
        }
        if (wv == 7) {
            h4f rh4;
            #pragma unroll
            for (int r = 0; r < 4; ++r) {
                const float s = pr[0][r][lane] + pr[1][r][lane]
                              + pr[2][r][lane] + pr[3][r][lane] + br4[r];
                const float rg = 1.f / (1.f + expf(-s));
                rh4[r] = (_Float16)(rg * hb[r][lane]);
            }
            if (l15 < 8)
                st8v(rbufg16 + (size_t)bcol * DIM + jbase + lgq * 4,
                     __builtin_bit_cast(f32x2, rh4));
        }
        // bar1: rh published / x consumed
        slot_bar(slots1g, bkg, (unsigned)(t + 1), dead);

        // ---- stage rh -> act x-half (pure copy, fp16) ----
        {
            f32x4 rv[2];
            #pragma unroll
            for (int q = 0; q < 2; ++q) {
                const int u = q * SCAN_THREADS + tid;
                ld4v(rv[q], (const float*)(rbufg16 + (size_t)(u >> 7) * DIM + (u & 127) * 8));
            }
            vmwait0();
            asm volatile("" : "+v"(rv[0]), "+v"(rv[1]));
            #pragma unroll
            for (int q = 0; q < 2; ++q) {
                const int u = q * SCAN_THREADS + tid;
                *(h8f*)&act[u >> 7][(u & 127) * 8] = __builtin_bit_cast(h8f, rv[q]);
            }
        }
        __syncthreads();

        // ---- Phase B: candB MFMA over rh (from LDS) ----
        if (wv == 4 || wv == 5) {
            const int kb2 = (wv - 4) * 512;
            f32x4 acc = {0.f, 0.f, 0.f, 0.f};
            #pragma unroll
            for (int kc = 0; kc < 16; ++kc) {
                const h8f bf = *(const h8f*)&act[bcol][kb2 + kc * 32 + lgq * 8];
                acc = __builtin_amdgcn_mfma_f32_16x16x32_f16(Wb[kc], bf, acc, 0, 0, 0);
            }
            #pragma unroll
            for (int r = 0; r < 4; ++r) pcb[wv - 4][r][lane] = acc[r];
        }
        __syncthreads();   // S2: candB partials ready

        // ---- update (w6): cand = tanh(cA+cB+b), h = z*h + (1-z)*cand ----
        if (wv == 6) {
            h4f hp; u16x4 yp;
            #pragma unroll
            for (int r = 0; r < 4; ++r) {
                const float cand = tanhf(pc[0][r][lane] + pc[1][r][lane]
                                         + pcb[0][r][lane] + pcb[1][r][lane] + cb4[r]);
                const float hn = zreg[r] * hold[r] + (1.f - zreg[r]) * cand;
                hold[r] = hn;
                hb[r][lane] = hn;
                hp[r] = (_Float16)hn;
                union { __hip_bfloat16 b; unsigned short u; } cv;
                cv.b = __float2bfloat16(hn);
                yp[r] = cv.u;
            }
            if (l15 < 8) {
                st8v(hdst16 + (size_t)bcol * DIM + jbase + lgq * 4,
                     __builtin_bit_cast(f32x2, hp));
                if (g == NGROUP - 1)
                    *(f32x2*)(ysfb + ((size_t)bcol * SEQ + t) * DIM + jbase + lgq * 4) =
                        __builtin_bit_cast(f32x2, yp);
            }
        }
        // bar2: h(t) published
        slot_bar(slots2g, bkg, (unsigned)(t + 2), dead);
    }

    if (dead && tid == 0) {
        union { __hip_bfloat16 b; unsigned short u; } cv;
        cv.b = __float2bfloat16(1.0e8f);
        ((unsigned short*)ysfb)[blockIdx.x] = cv.u;   // unmistakable sentinel
    }
}

// ---------------------------------------------------------------------------
// Logits GEMM, both inputs bf16: C[m][n] = sum_k A[m][k] * B[n][k]
// ---------------------------------------------------------------------------
#define BM 128
#define BN 128
#define BK 64

__global__ void __launch_bounds__(256) out_gemm_bb(
    const __hip_bfloat16* __restrict__ A,   // [4096][1024] bf16
    const __hip_bfloat16* __restrict__ B,   // [32000][1024] bf16
    float* __restrict__ C)                  // [4096][32000]
{
    __shared__ __hip_bfloat16 At[BM][BK + 8];
    __shared__ __hip_bfloat16 Bt[BN][BK + 8];

    const int tid  = threadIdx.x;
    const int lane = tid & 63;
    const int wv   = tid >> 6;
    const int wm   = wv >> 1, wn = wv & 1;
    const int m0   = blockIdx.y * BM;
    const int n0   = blockIdx.x * BN;

    f32x4 acc[4][4];
    #pragma unroll
    for (int i = 0; i < 4; ++i)
        #pragma unroll
        for (int jj = 0; jj < 4; ++jj)
            acc[i][jj] = (f32x4){0.f, 0.f, 0.f, 0.f};

    const int srow = tid >> 3;           // 0..31
    const int scol = (tid & 7) * 8;      // 0..56
    const int l15  = lane & 15;
    const int l4   = lane >> 4;

    for (int kt = 0; kt < DIM / BK; ++kt) {
        const int k0 = kt * BK;
        #pragma unroll
        for (int rnd = 0; rnd < 4; ++rnd) {
            const int row = rnd * 32 + srow;
            *(u16x8*)&At[row][scol] =
                *(const u16x8*)&A[(size_t)(m0 + row) * DIM + k0 + scol];
            *(u16x8*)&Bt[row][scol] =
                *(const u16x8*)&B[(size_t)(n0 + row) * DIM + k0 + scol];
        }
        __syncthreads();
        #pragma unroll
        for (int ks = 0; ks < 2; ++ks) {
            bf16x8 av[4], bv[4];
            #pragma unroll
            for (int i = 0; i < 4; ++i) {
                av[i] = *(const bf16x8*)&At[wm * 64 + i * 16 + l15][ks * 32 + l4 * 8];
                bv[i] = *(const bf16x8*)&Bt[wn * 64 + i * 16 + l15][ks * 32 + l4 * 8];
            }
            #pragma unroll
            for (int i = 0; i < 4; ++i)
                #pragma unroll
                for (int jj = 0; jj < 4; ++jj)
                    acc[i][jj] = __builtin_amdgcn_mfma_f32_16x16x32_bf16(
                        av[i], bv[jj], acc[i][jj], 0, 0, 0);
        }
        __syncthreads();
    }

    const int rq = l4 * 4;
    #pragma unroll
    for (int i = 0; i < 4; ++i) {
        const int rbase = m0 + wm * 64 + i * 16 + rq;
        #pragma unroll
        for (int jj = 0; jj < 4; ++jj) {
            const int col = n0 + wn * 64 + jj * 16 + l15;
            #pragma unroll
            for (int r2 = 0; r2 < 4; ++r2)
                C[(size_t)(rbase + r2) * VOCAB + col] = acc[i][jj][r2];
        }
    }
}

// ---------------------------------------------------------------------------
// Fallback GEMM (round-16 form): A bf16, B fp32 converted during staging.
// ---------------------------------------------------------------------------
__global__ void __launch_bounds__(256) out_gemm_bf(
    const __hip_bfloat16* __restrict__ A,   // [4096][1024] bf16
    const float* __restrict__ B,            // [32000][1024] fp32
    float* __restrict__ C)                  // [4096][32000]
{
    __shared__ __hip_bfloat16 At[BM][BK + 8];
    __shared__ __hip_bfloat16 Bt[BN][BK + 8];

    const int tid  = threadIdx.x;
    const int lane = tid & 63;
    const int wv   = tid >> 6;
    const int wm   = wv >> 1, wn = wv & 1;
    const int m0   = blockIdx.y * BM;
    const int n0   = blockIdx.x * BN;

    f32x4 acc[4][4];
    #pragma unroll
    for (int i = 0; i < 4; ++i)
        #pragma unroll
        for (int jj = 0; jj < 4; ++jj)
            acc[i][jj] = (f32x4){0.f, 0.f, 0.f, 0.f};

    const int srow = tid >> 3;
    const int scol = (tid & 7) * 8;
    const int l15  = lane & 15;
    const int l4   = lane >> 4;

    for (int kt = 0; kt < DIM / BK; ++kt) {
        const int k0 = kt * BK;
        #pragma unroll
        for (int rnd = 0; rnd < 4; ++rnd) {
            const int row = rnd * 32 + srow;
            *(u16x8*)&At[row][scol] =
                *(const u16x8*)&A[(size_t)(m0 + row) * DIM + k0 + scol];
            *(u16x8*)&Bt[row][scol] =
                cvt8_bf16(&B[(size_t)(n0 + row) * DIM + k0 + scol]);
        }
        __syncthreads();
        #pragma unroll
        for (int ks = 0; ks < 2; ++ks) {
            bf16x8 av[4], bv[4];
            #pragma unroll
            for (int i = 0; i < 4; ++i) {
                av[i] = *(const bf16x8*)&At[wm * 64 + i * 16 + l15][ks * 32 + l4 * 8];
                bv[i] = *(const bf16x8*)&Bt[wn * 64 + i * 16 + l15][ks * 32 + l4 * 8];
            }
            #pragma unroll
            for (int i = 0; i < 4; ++i)
                #pragma unroll
                for (int jj = 0; jj < 4; ++jj)
                    acc[i][jj] = __builtin_amdgcn_mfma_f32_16x16x32_bf16(
                        av[i], bv[jj], acc[i][jj], 0, 0, 0);
        }
        __syncthreads();
    }

    const int rq = l4 * 4;
    #pragma unroll
    for (int i = 0; i < 4; ++i) {
        const int rbase = m0 + wm * 64 + i * 16 + rq;
        #pragma unroll
        for (int jj = 0; jj < 4; ++jj) {
            const int col = n0 + wn * 64 + jj * 16 + l15;
            #pragma unroll
            for (int r2 = 0; r2 < 4; ++r2)
                C[(size_t)(rbase + r2) * VOCAB + col] = acc[i][jj][r2];
        }
    }
}

// ---------------------------------------------------------------------------
extern "C" void kernel_launch(void* const* d_in, const int* in_sizes, int n_in,
                              void* d_out, int out_size, void* d_ws, size_t ws_size,
                              hipStream_t stream)
{
    (void)in_sizes; (void)n_in; (void)out_size;
    const int*   ids  = (const int*)  d_in[0];
    const float* embW = (const float*)d_in[1];
    const float* hst  = (const float*)d_in[2];
    const float* gW   = (const float*)d_in[3];
    const float* gB   = (const float*)d_in[4];
    const float* cW   = (const float*)d_in[5];
    const float* cB   = (const float*)d_in[6];
    const float* outW = (const float*)d_in[7];
    float* logits = (float*)d_out;

    // workspace carve-up
    char* ws = (char*)d_ws;
    unsigned*       bar    = (unsigned*)ws;                       // 16 KiB
    _Float16*       rbuf16 = (_Float16*)(ws + 16384);             // 64 KiB
    _Float16*       hbuf16 = (_Float16*)(ws + 16384 + 65536);     // 256 KiB
    __hip_bfloat16* ysfb   = (__hip_bfloat16*)(ws + 16384 + 65536 + 262144);  // 8 MiB
    const size_t outWb_off = 16384 + 65536 + 262144 + (size_t)NB * SEQ * DIM * 2;
    const size_t need      = outWb_off + (size_t)VOCAB * DIM * 2;   // ~74.3 MB
    const int doConv = (ws_size >= need) ? 1 : 0;
    __hip_bfloat16* outWb = doConv ? (__hip_bfloat16*)(ws + outWb_off) : nullptr;

    // 1) zero slot arrays
    bar_init_kernel<<<dim3(1), dim3(1024), 0, stream>>>(bar);

    // 2) GRU scan (r16 structure; groups 1-3 convert out_W->bf16 during fill)
    gru_scan<<<dim3(SCAN_BLOCKS), dim3(SCAN_THREADS), 0, stream>>>(
        ids, embW, hst, gW, gB, cW, cB, hbuf16, rbuf16, ysfb, bar,
        outW, outWb, doConv);

    // 3) logits GEMM
    if (doConv)
        out_gemm_bb<<<dim3(VOCAB / BN, (NB * SEQ) / BM), dim3(256), 0, stream>>>(
            ysfb, outWb, logits);
    else
        out_gemm_bf<<<dim3(VOCAB / BN, (NB * SEQ) / BM), dim3(256), 0, stream>>>(
            ysfb, outW, logits);
}

// Round 18
// 3479.765 us; speedup vs baseline: 1.9390x; 1.0069x over previous
//
#include <hip/hip_runtime.h>
#include <hip/hip_bf16.h>

#define VOCAB  32000
#define DIM    1024
#define NLAYER 4
#define NB     8
#define SEQ    512

#define NGROUP       4
#define GBLKS        64
#define SCAN_BLOCKS  (NGROUP * GBLKS)      // 256
#define SCAN_THREADS 512                   // 8 waves, role-split
#define ROWH         2056                  // act row stride (2048 + 8 pad halves)

typedef __attribute__((ext_vector_type(8))) short          bf16x8;
typedef __attribute__((ext_vector_type(4))) float          f32x4;
typedef __attribute__((ext_vector_type(2))) float          f32x2;
typedef __attribute__((ext_vector_type(8))) unsigned short u16x8;
typedef __attribute__((ext_vector_type(4))) unsigned short u16x4;
typedef __attribute__((ext_vector_type(8))) _Float16       h8f;
typedef __attribute__((ext_vector_type(4))) _Float16       h4f;

__device__ __forceinline__ u16x8 cvt8_bf16(const float* p) {
    float4 f0 = *(const float4*)p;
    float4 f1 = *(const float4*)(p + 4);
    union { __hip_bfloat16 h[8]; u16x8 v; } u;
    u.h[0] = __float2bfloat16(f0.x); u.h[1] = __float2bfloat16(f0.y);
    u.h[2] = __float2bfloat16(f0.z); u.h[3] = __float2bfloat16(f0.w);
    u.h[4] = __float2bfloat16(f1.x); u.h[5] = __float2bfloat16(f1.y);
    u.h[6] = __float2bfloat16(f1.z); u.h[7] = __float2bfloat16(f1.w);
    return u.v;
}

__device__ __forceinline__ h8f pack8(f32x4 a, f32x4 b) {
    h8f o;
    o[0] = (_Float16)a[0]; o[1] = (_Float16)a[1];
    o[2] = (_Float16)a[2]; o[3] = (_Float16)a[3];
    o[4] = (_Float16)b[0]; o[5] = (_Float16)b[1];
    o[6] = (_Float16)b[2]; o[7] = (_Float16)b[3];
    return o;
}

// ---- coherence-point (L3) accesses: bypass per-XCD L2 (no cache fences) ----
__device__ __forceinline__ void ld4v(f32x4& d, const float* p) {
    asm volatile("global_load_dwordx4 %0, %1, off sc0 sc1"
                 : "=&v"(d) : "v"(p));
}
__device__ __forceinline__ void st8v(void* p, f32x2 v) {
    asm volatile("global_store_dwordx2 %0, %1, off sc0 sc1"
                 :: "v"(p), "v"(v) : "memory");
}
__device__ __forceinline__ void st2v(void* p, unsigned v) {
    asm volatile("global_store_short %0, %1, off sc0 sc1"
                 :: "v"(p), "v"(v) : "memory");
}
__device__ __forceinline__ void vmwait0() {
    asm volatile("s_waitcnt vmcnt(0)" ::: "memory");
}

// ---- async global -> LDS, 16 B per lane (dest = wave-uniform base + lane*16)
__device__ __forceinline__ void gload_lds16(const void* g, void* l) {
    __builtin_amdgcn_global_load_lds(
        (const __attribute__((address_space(1))) void*)g,
        (__attribute__((address_space(3))) void*)l, 16, 0, 0);
}

// ---------------------------------------------------------------------------
__global__ void bar_init_kernel(unsigned* __restrict__ bar) {
    bar[threadIdx.x]        = 0u;
    bar[threadIdx.x + 1024] = 0u;
    bar[threadIdx.x + 2048] = 0u;
    bar[threadIdx.x + 3072] = 0u;   // 4096 words = 16 KiB
}

// ---------------------------------------------------------------------------
// Fence-free slot barrier (round-12 form — proven best).
// ---------------------------------------------------------------------------
__device__ __forceinline__ void slot_bar(unsigned* __restrict__ slots, int bkg,
                                         unsigned seq, bool& dead) {
    __syncthreads();
    const int tid = threadIdx.x;
    if (tid == 0)
        __hip_atomic_store(&slots[bkg * 8], seq, __ATOMIC_RELAXED,
                           __HIP_MEMORY_SCOPE_AGENT);
    if (tid < 64 && !dead) {
        unsigned guard = 0;
        for (;;) {
            unsigned v = __hip_atomic_load(&slots[tid * 8], __ATOMIC_RELAXED,
                                           __HIP_MEMORY_SCOPE_AGENT);
            if (__all((int)(v >= seq))) break;
            __builtin_amdgcn_s_sleep(1);
            if (++guard > (1u << 16)) { dead = true; break; }
        }
    }
    __syncthreads();
}

// ---------------------------------------------------------------------------
// MFMA layer-pipelined persistent-weight GRU scan — round-17 (byte-identical).
// ---------------------------------------------------------------------------
__global__ void __launch_bounds__(SCAN_THREADS)
__attribute__((amdgpu_waves_per_eu(2, 2)))
gru_scan(
    const int*   __restrict__ ids,     // [NB][SEQ]
    const float* __restrict__ embW,    // [VOCAB][DIM] fp32
    const float* __restrict__ hstart,  // [NLAYER][DIM]
    const float* __restrict__ gW,      // [NLAYER][2*DIM][2*DIM]
    const float* __restrict__ gB,      // [NLAYER][2*DIM]
    const float* __restrict__ cW,      // [NLAYER][DIM][2*DIM]
    const float* __restrict__ cB,      // [NLAYER][DIM]
    _Float16* __restrict__ hbuf16,     // [4][NLAYER][NB][DIM] fp16 ring
    _Float16* __restrict__ rbuf16,     // [NGROUP][NB][DIM] fp16 (rh)
    __hip_bfloat16* __restrict__ ysfb, // [NB][SEQ][DIM] bf16
    unsigned* __restrict__ bar,
    const float* __restrict__ outW,    // [VOCAB][DIM] fp32
    __hip_bfloat16* __restrict__ outWb,// [VOCAB][DIM] bf16 (ws) or null
    int doConv)
{
    __shared__ _Float16 act[NB][ROWH];     // 32,896 B: x [0,1024) | h [1024,2048)
    __shared__ float pz[4][4][64];
    __shared__ float pr[4][4][64];
    __shared__ float pc[2][4][64];
    __shared__ float pcb[2][4][64];
    __shared__ float hb[4][64];            // h(t-1) handoff w6 -> w7

    const int tid   = threadIdx.x;
    const int lane  = tid & 63;
    const int wv    = tid >> 6;               // 0..7
    const int l15   = lane & 15;
    const int lgq   = lane >> 4;              // 0..3
    const int bcol  = l15 & 7;                // batch (cols 8..15 dup 0..7)
    const int g     = blockIdx.x >> 6;        // layer group
    const int bkg   = blockIdx.x & (GBLKS-1);
    const int jbase = bkg * 16;
    const int jrow  = jbase + l15;            // this lane's A row

    // ---- out_W conversion by pipeline-idle groups 1-3 (before anything) ----
    if (doConv && g > 0) {
        const int cidx = (blockIdx.x - GBLKS) * SCAN_THREADS + tid;  // 0..98303
        for (int u = cidx; u < VOCAB * DIM / 8; u += (SCAN_BLOCKS - GBLKS) * SCAN_THREADS)
            ((u16x8*)outWb)[u] = cvt8_bf16(outW + (size_t)u * 8);
    }

    // ---- persistent fp16 A-fragment weights (pinned; unified VGPR/AGPR) ----
    h8f Wa[16], Wb[16];
    if (wv < 6) {
        const float* wzp = gW + ((size_t)g * 2048 + jrow) * 2048;
        const float* wrp = gW + ((size_t)g * 2048 + 1024 + jrow) * 2048;
        const float* wcp = cW + ((size_t)g * 1024 + jrow) * 2048;
        const float* baseA; const float* baseB; int koA, koB;
        switch (wv) {
          case 0:  baseA = wzp; koA = 0;    baseB = wrp; koB = 0;    break;
          case 1:  baseA = wzp; koA = 512;  baseB = wrp; koB = 512;  break;
          case 2:  baseA = wzp; koA = 1024; baseB = wrp; koB = 1024; break;
          case 3:  baseA = wzp; koA = 1536; baseB = wrp; koB = 1536; break;
          case 4:  baseA = wcp; koA = 0;    baseB = wcp; koB = 1024; break;
          default: baseA = wcp; koA = 512;  baseB = wcp; koB = 1536; break;
        }
        #pragma unroll
        for (int kc = 0; kc < 16; ++kc) {
            const int ka = koA + kc * 32 + lgq * 8;
            const int kb = koB + kc * 32 + lgq * 8;
            Wa[kc] = pack8(*(const f32x4*)(baseA + ka), *(const f32x4*)(baseA + ka + 4));
            Wb[kc] = pack8(*(const f32x4*)(baseB + kb), *(const f32x4*)(baseB + kb + 4));
        }
        #pragma unroll
        for (int kc = 0; kc < 16; ++kc) {
            asm volatile("" : "+v"(Wa[kc]));
            asm volatile("" : "+v"(Wb[kc]));
        }
    }

    float bz4[4], br4[4], cb4[4], hold[4], zreg[4];
    if (wv == 6) {
        #pragma unroll
        for (int r = 0; r < 4; ++r) {
            const int j = jbase + lgq * 4 + r;
            bz4[r]  = gB[g * 2048 + j];
            cb4[r]  = cB[g * 1024 + j];
            hold[r] = hstart[g * 1024 + j];
            hb[r][lane] = hold[r];
        }
    }
    if (wv == 7) {
        #pragma unroll
        for (int r = 0; r < 4; ++r)
            br4[r] = gB[g * 2048 + 1024 + jbase + lgq * 4 + r];
    }

    bool dead = false;
    unsigned* slots1g = bar + g * 512;
    unsigned* slots2g = bar + 2048 + g * 512;
    unsigned* s2prev  = (g > 0)          ? bar + 2048 + (g - 1) * 512 : nullptr;
    unsigned* s1next  = (g < NGROUP - 1) ? bar + (g + 1) * 512        : nullptr;
    _Float16* rbufg16 = rbuf16 + (size_t)g * NB * DIM;

    // init own layer h(-1) into ring slot 3 (fp16, sc1)
    if (tid < 128) {
        int e = bkg * 128 + tid;   // 0..8191 over [NB][DIM]
        union { _Float16 h; unsigned short u; } cv;
        cv.h = (_Float16)hstart[g * DIM + (e & (DIM - 1))];
        st2v(&hbuf16[((size_t)3 * NLAYER + g) * NB * DIM + e], (unsigned)cv.u);
    }
    slot_bar(slots2g, bkg, 1u, dead);

    for (int t = 0; t < SEQ; ++t) {
        const int so = (t + 3) & 3;   // h_old slot
        const int sw = t & 3;         // h_new slot
        const _Float16* hsrc16  = hbuf16 + ((size_t)so * NLAYER + g) * NB * DIM;
        _Float16*       hdst16  = hbuf16 + ((size_t)sw * NLAYER + g) * NB * DIM;
        const _Float16* xprev16 = hbuf16 + ((size_t)sw * NLAYER + (g > 0 ? g - 1 : 0)) * NB * DIM;

        // ---- peer gates (round-12 combined form) ----
        {
            const unsigned need_a = (g > 0) ? (unsigned)(t + 2) : 0u;
            const unsigned need_b = (g < NGROUP - 1 && t >= 4) ? (unsigned)(t - 3) : 0u;
            if (tid < 64 && !dead && (need_a | need_b)) {
                unsigned guard = 0;
                for (;;) {
                    bool ok = true;
                    if (need_a)
                        ok &= (__hip_atomic_load(&s2prev[tid * 8], __ATOMIC_RELAXED,
                                                 __HIP_MEMORY_SCOPE_AGENT) >= need_a);
                    if (need_b)
                        ok &= (__hip_atomic_load(&s1next[tid * 8], __ATOMIC_RELAXED,
                                                 __HIP_MEMORY_SCOPE_AGENT) >= need_b);
                    if (__all((int)ok)) break;
                    __builtin_amdgcn_s_sleep(1);
                    if (++guard > (1u << 16)) { dead = true; break; }
                }
            }
            __syncthreads();
        }

        // ---- stage x -> act[.][0:1024) and h_old -> act[.][1024:2048) ----
        if (g == 0) {
            #pragma unroll
            for (int q = 0; q < 2; ++q) {
                const int u = q * SCAN_THREADS + tid;   // 0..1023
                const int b = u >> 7, d8 = (u & 127) * 8;
                const float* p = embW + (size_t)ids[b * SEQ + t] * DIM + d8;
                *(h8f*)&act[b][d8] = pack8(*(const f32x4*)p, *(const f32x4*)(p + 4));
            }
            f32x4 hv[2];
            #pragma unroll
            for (int q = 0; q < 2; ++q) {
                const int u = q * SCAN_THREADS + tid;
                ld4v(hv[q], (const float*)(hsrc16 + (size_t)(u >> 7) * DIM + (u & 127) * 8));
            }
            vmwait0();
            asm volatile("" : "+v"(hv[0]), "+v"(hv[1]));
            #pragma unroll
            for (int q = 0; q < 2; ++q) {
                const int u = q * SCAN_THREADS + tid;
                *(h8f*)&act[u >> 7][1024 + (u & 127) * 8] = __builtin_bit_cast(h8f, hv[q]);
            }
        } else {
            f32x4 xv[2], hv[2];
            #pragma unroll
            for (int q = 0; q < 2; ++q) {
                const int u = q * SCAN_THREADS + tid;
                ld4v(xv[q], (const float*)(xprev16 + (size_t)(u >> 7) * DIM + (u & 127) * 8));
                ld4v(hv[q], (const float*)(hsrc16 + (size_t)(u >> 7) * DIM + (u & 127) * 8));
            }
            vmwait0();
            asm volatile("" : "+v"(xv[0]), "+v"(xv[1]), "+v"(hv[0]), "+v"(hv[1]));
            #pragma unroll
            for (int q = 0; q < 2; ++q) {
                const int u = q * SCAN_THREADS + tid;
                const int b = u >> 7, d8 = (u & 127) * 8;
                *(h8f*)&act[b][d8]        = __builtin_bit_cast(h8f, xv[q]);
                *(h8f*)&act[b][1024 + d8] = __builtin_bit_cast(h8f, hv[q]);
            }
        }
        __syncthreads();   // S0: act staged

        // ---- Phase A: MFMA dots (B-operands from LDS) ----
        if (wv < 6) {
            const int kb2 = (wv < 4) ? wv * 512 : (wv - 4) * 512;
            f32x4 accA = {0.f, 0.f, 0.f, 0.f};
            f32x4 accB = {0.f, 0.f, 0.f, 0.f};
            #pragma unroll
            for (int kc = 0; kc < 16; ++kc) {
                const h8f bf = *(const h8f*)&act[bcol][kb2 + kc * 32 + lgq * 8];
                accA = __builtin_amdgcn_mfma_f32_16x16x32_f16(Wa[kc], bf, accA, 0, 0, 0);
                if (wv < 4)
                    accB = __builtin_amdgcn_mfma_f32_16x16x32_f16(Wb[kc], bf, accB, 0, 0, 0);
            }
            if (wv < 4) {
                #pragma unroll
                for (int r = 0; r < 4; ++r) {
                    pz[wv][r][lane] = accA[r];
                    pr[wv][r][lane] = accB[r];
                }
            } else {
                #pragma unroll
                for (int r = 0; r < 4; ++r) pc[wv - 4][r][lane] = accA[r];
            }
        }
        __syncthreads();   // S1: partials ready

        // ---- combine: z (w6, regs) ; r -> rh publish (w7, fp16 sc1) ----
        if (wv == 6) {
            #pragma unroll
            for (int r = 0; r < 4; ++r) {
                const float s = pz[0][r][lane] + pz[1][r][lane]
                              + pz[2][r][lane] + pz[3][r][lane] + bz4[r];
                zreg[r] = 1.f / (1.f + expf(-s));
            }
        }
        if (wv == 7) {
            h4f rh4;
            #pragma unroll
            for (int r = 0; r < 4; ++r) {
                const float s = pr[0][r][lane] + pr[1][r][lane]
                              + pr[2][r][lane] + pr[3][r][lane] + br4[r];
                const float rg = 1.f / (1.f + expf(-s));
                rh4[r] = (_Float16)(rg * hb[r][lane]);
            }
            if (l15 < 8)
                st8v(rbufg16 + (size_t)bcol * DIM + jbase + lgq * 4,
                     __builtin_bit_cast(f32x2, rh4));
        }
        // bar1: rh published / x consumed
        slot_bar(slots1g, bkg, (unsigned)(t + 1), dead);

        // ---- stage rh -> act x-half (pure copy, fp16) ----
        {
            f32x4 rv[2];
            #pragma unroll
            for (int q = 0; q < 2; ++q) {
                const int u = q * SCAN_THREADS + tid;
                ld4v(rv[q], (const float*)(rbufg16 + (size_t)(u >> 7) * DIM + (u & 127) * 8));
            }
            vmwait0();
            asm volatile("" : "+v"(rv[0]), "+v"(rv[1]));
            #pragma unroll
            for (int q = 0; q < 2; ++q) {
                const int u = q * SCAN_THREADS + tid;
                *(h8f*)&act[u >> 7][(u & 127) * 8] = __builtin_bit_cast(h8f, rv[q]);
            }
        }
        __syncthreads();

        // ---- Phase B: candB MFMA over rh (from LDS) ----
        if (wv == 4 || wv == 5) {
            const int kb2 = (wv - 4) * 512;
            f32x4 acc = {0.f, 0.f, 0.f, 0.f};
            #pragma unroll
            for (int kc = 0; kc < 16; ++kc) {
                const h8f bf = *(const h8f*)&act[bcol][kb2 + kc * 32 + lgq * 8];
                acc = __builtin_amdgcn_mfma_f32_16x16x32_f16(Wb[kc], bf, acc, 0, 0, 0);
            }
            #pragma unroll
            for (int r = 0; r < 4; ++r) pcb[wv - 4][r][lane] = acc[r];
        }
        __syncthreads();   // S2: candB partials ready

        // ---- update (w6): cand = tanh(cA+cB+b), h = z*h + (1-z)*cand ----
        if (wv == 6) {
            h4f hp; u16x4 yp;
            #pragma unroll
            for (int r = 0; r < 4; ++r) {
                const float cand = tanhf(pc[0][r][lane] + pc[1][r][lane]
                                         + pcb[0][r][lane] + pcb[1][r][lane] + cb4[r]);
                const float hn = zreg[r] * hold[r] + (1.f - zreg[r]) * cand;
                hold[r] = hn;
                hb[r][lane] = hn;
                hp[r] = (_Float16)hn;
                union { __hip_bfloat16 b; unsigned short u; } cv;
                cv.b = __float2bfloat16(hn);
                yp[r] = cv.u;
            }
            if (l15 < 8) {
                st8v(hdst16 + (size_t)bcol * DIM + jbase + lgq * 4,
                     __builtin_bit_cast(f32x2, hp));
                if (g == NGROUP - 1)
                    *(f32x2*)(ysfb + ((size_t)bcol * SEQ + t) * DIM + jbase + lgq * 4) =
                        __builtin_bit_cast(f32x2, yp);
            }
        }
        // bar2: h(t) published
        slot_bar(slots2g, bkg, (unsigned)(t + 2), dead);
    }

    if (dead && tid == 0) {
        union { __hip_bfloat16 b; unsigned short u; } cv;
        cv.b = __float2bfloat16(1.0e8f);
        ((unsigned short*)ysfb)[blockIdx.x] = cv.u;   // unmistakable sentinel
    }
}

// ---------------------------------------------------------------------------
// Logits GEMM, both bf16, m97-style global_load_lds staging + XCD swizzle.
// C[m][n] = sum_k A[m][k] * B[n][k];  grid = 8000 1-D blocks (250 n x 32 m).
// ---------------------------------------------------------------------------
#define BM 128
#define BN 128
#define BK 64

__global__ void __launch_bounds__(256) out_gemm_bb(
    const __hip_bfloat16* __restrict__ A,   // [4096][1024] bf16
    const __hip_bfloat16* __restrict__ B,   // [32000][1024] bf16
    float* __restrict__ C)                  // [4096][32000]
{
    __shared__ __hip_bfloat16 At[BM][BK];   // 16 KB, linear (gload_lds dest)
    __shared__ __hip_bfloat16 Bt[BN][BK];   // 16 KB

    const int tid  = threadIdx.x;
    const int lane = tid & 63;
    const int wv   = tid >> 6;             // 0..3
    const int wm   = wv >> 1, wn = wv & 1;
    const int l15  = lane & 15;
    const int l4   = lane >> 4;

    // bijective XCD swizzle: 8000 % 8 == 0; XCD k owns 4 contiguous M-rows
    const int swz = (blockIdx.x & 7) * 1000 + (blockIdx.x >> 3);
    const int n0  = (swz % 250) * BN;
    const int m0  = (swz / 250) * BM;

    f32x4 acc[4][4];
    #pragma unroll
    for (int i = 0; i < 4; ++i)
        #pragma unroll
        for (int jj = 0; jj < 4; ++jj)
            acc[i][jj] = (f32x4){0.f, 0.f, 0.f, 0.f};

    // staging geometry: tile = 1024 16B units; unit u = r*256 + wv*64 + lane
    // row = u>>3, col8 = u&7; LDS byte = u*16 = wave-uniform base + lane*16.
    const int srow = (tid >> 3);           // u>>3 for r=0 is tid>>3
    const int scol = (tid & 7) * 8;

    for (int kt = 0; kt < DIM / BK; ++kt) {
        const int k0 = kt * BK;
        #pragma unroll
        for (int r = 0; r < 4; ++r) {
            const int row = r * 32 + srow;               // u>>3
            gload_lds16(&A[(size_t)(m0 + row) * DIM + k0 + scol],
                        &At[r * 32 + wv * 8][0]);
            gload_lds16(&B[(size_t)(n0 + row) * DIM + k0 + scol],
                        &Bt[r * 32 + wv * 8][0]);
        }
        __syncthreads();   // compiler drains vmcnt before s_barrier
        #pragma unroll
        for (int ks = 0; ks < 2; ++ks) {
            bf16x8 av[4], bv[4];
            #pragma unroll
            for (int i = 0; i < 4; ++i) {
                av[i] = *(const bf16x8*)&At[wm * 64 + i * 16 + l15][ks * 32 + l4 * 8];
                bv[i] = *(const bf16x8*)&Bt[wn * 64 + i * 16 + l15][ks * 32 + l4 * 8];
            }
            #pragma unroll
            for (int i = 0; i < 4; ++i)
                #pragma unroll
                for (int jj = 0; jj < 4; ++jj)
                    acc[i][jj] = __builtin_amdgcn_mfma_f32_16x16x32_bf16(
                        av[i], bv[jj], acc[i][jj], 0, 0, 0);
        }
        __syncthreads();
    }

    const int rq = l4 * 4;
    #pragma unroll
    for (int i = 0; i < 4; ++i) {
        const int rbase = m0 + wm * 64 + i * 16 + rq;
        #pragma unroll
        for (int jj = 0; jj < 4; ++jj) {
            const int col = n0 + wn * 64 + jj * 16 + l15;
            #pragma unroll
            for (int r2 = 0; r2 < 4; ++r2)
                C[(size_t)(rbase + r2) * VOCAB + col] = acc[i][jj][r2];
        }
    }
}

// ---------------------------------------------------------------------------
// Fallback GEMM (round-16 form): A bf16, B fp32 converted during staging.
// ---------------------------------------------------------------------------
__global__ void __launch_bounds__(256) out_gemm_bf(
    const __hip_bfloat16* __restrict__ A,   // [4096][1024] bf16
    const float* __restrict__ B,            // [32000][1024] fp32
    float* __restrict__ C)                  // [4096][32000]
{
    __shared__ __hip_bfloat16 At[BM][BK + 8];
    __shared__ __hip_bfloat16 Bt[BN][BK + 8];

    const int tid  = threadIdx.x;
    const int lane = tid & 63;
    const int wv   = tid >> 6;
    const int wm   = wv >> 1, wn = wv & 1;
    const int m0   = blockIdx.y * BM;
    const int n0   = blockIdx.x * BN;

    f32x4 acc[4][4];
    #pragma unroll
    for (int i = 0; i < 4; ++i)
        #pragma unroll
        for (int jj = 0; jj < 4; ++jj)
            acc[i][jj] = (f32x4){0.f, 0.f, 0.f, 0.f};

    const int srow = tid >> 3;
    const int scol = (tid & 7) * 8;
    const int l15  = lane & 15;
    const int l4   = lane >> 4;

    for (int kt = 0; kt < DIM / BK; ++kt) {
        const int k0 = kt * BK;
        #pragma unroll
        for (int rnd = 0; rnd < 4; ++rnd) {
            const int row = rnd * 32 + srow;
            *(u16x8*)&At[row][scol] =
                *(const u16x8*)&A[(size_t)(m0 + row) * DIM + k0 + scol];
            *(u16x8*)&Bt[row][scol] =
                cvt8_bf16(&B[(size_t)(n0 + row) * DIM + k0 + scol]);
        }
        __syncthreads();
        #pragma unroll
        for (int ks = 0; ks < 2; ++ks) {
            bf16x8 av[4], bv[4];
            #pragma unroll
            for (int i = 0; i < 4; ++i) {
                av[i] = *(const bf16x8*)&At[wm * 64 + i * 16 + l15][ks * 32 + l4 * 8];
                bv[i] = *(const bf16x8*)&Bt[wn * 64 + i * 16 + l15][ks * 32 + l4 * 8];
            }
            #pragma unroll
            for (int i = 0; i < 4; ++i)
                #pragma unroll
                for (int jj = 0; jj < 4; ++jj)
                    acc[i][jj] = __builtin_amdgcn_mfma_f32_16x16x32_bf16(
                        av[i], bv[jj], acc[i][jj], 0, 0, 0);
        }
        __syncthreads();
    }

    const int rq = l4 * 4;
    #pragma unroll
    for (int i = 0; i < 4; ++i) {
        const int rbase = m0 + wm * 64 + i * 16 + rq;
        #pragma unroll
        for (int jj = 0; jj < 4; ++jj) {
            const int col = n0 + wn * 64 + jj * 16 + l15;
            #pragma unroll
            for (int r2 = 0; r2 < 4; ++r2)
                C[(size_t)(rbase + r2) * VOCAB + col] = acc[i][jj][r2];
        }
    }
}

// ---------------------------------------------------------------------------
extern "C" void kernel_launch(void* const* d_in, const int* in_sizes, int n_in,
                              void* d_out, int out_size, void* d_ws, size_t ws_size,
                              hipStream_t stream)
{
    (void)in_sizes; (void)n_in; (void)out_size;
    const int*   ids  = (const int*)  d_in[0];
    const float* embW = (const float*)d_in[1];
    const float* hst  = (const float*)d_in[2];
    const float* gW   = (const float*)d_in[3];
    const float* gB   = (const float*)d_in[4];
    const float* cW   = (const float*)d_in[5];
    const float* cB   = (const float*)d_in[6];
    const float* outW = (const float*)d_in[7];
    float* logits = (float*)d_out;

    // workspace carve-up
    char* ws = (char*)d_ws;
    unsigned*       bar    = (unsigned*)ws;                       // 16 KiB
    _Float16*       rbuf16 = (_Float16*)(ws + 16384);             // 64 KiB
    _Float16*       hbuf16 = (_Float16*)(ws + 16384 + 65536);     // 256 KiB
    __hip_bfloat16* ysfb   = (__hip_bfloat16*)(ws + 16384 + 65536 + 262144);  // 8 MiB
    const size_t outWb_off = 16384 + 65536 + 262144 + (size_t)NB * SEQ * DIM * 2;
    const size_t need      = outWb_off + (size_t)VOCAB * DIM * 2;   // ~74.3 MB
    const int doConv = (ws_size >= need) ? 1 : 0;
    __hip_bfloat16* outWb = doConv ? (__hip_bfloat16*)(ws + outWb_off) : nullptr;

    // 1) zero slot arrays
    bar_init_kernel<<<dim3(1), dim3(1024), 0, stream>>>(bar);

    // 2) GRU scan (r17; groups 1-3 convert out_W->bf16 during pipeline fill)
    gru_scan<<<dim3(SCAN_BLOCKS), dim3(SCAN_THREADS), 0, stream>>>(
        ids, embW, hst, gW, gB, cW, cB, hbuf16, rbuf16, ysfb, bar,
        outW, outWb, doConv);

    // 3) logits GEMM
    if (doConv)
        out_gemm_bb<<<dim3((VOCAB / BN) * ((NB * SEQ) / BM)), dim3(256), 0, stream>>>(
            ysfb, outWb, logits);
    else
        out_gemm_bf<<<dim3(VOCAB / BN, (NB * SEQ) / BM), dim3(256), 0, stream>>>(
            ysfb, outW, logits);
}